// Round 15
// baseline (5397.958 us; speedup 1.0000x reference)
//
#include <hip/hip_runtime.h>
#include <hip/hip_bf16.h>
#include <stdint.h>

// ---- problem constants ----
constexpr int LI   = 128;    // L_IN
constexpr int LO   = 64;     // L_OUT
constexpr int NB   = 32;     // batch
constexpr int HD   = 1024;   // H
constexpr int HHD  = 512;    // HH
constexpr int NLAY = 2;
constexpr int NV   = 32000;  // V_OUT
constexpr int SOST = 1;

// Round-15: encoder converted to per-step launches (the mechanism that won
// the round-14 decoder A/B: kernel boundary = free coherence, ~2-3us vs
// ~9-25us software barriers). Plain loads/stores on per-step h slots; no
// atomics/flags in the encoder at all. Decoder/GEMMs = round-14 (passing).

typedef __hip_bfloat16 bf16;
typedef __attribute__((ext_vector_type(8))) short bf16x8;
typedef __attribute__((ext_vector_type(4))) float f32x4;
typedef unsigned long long u64;

constexpr int BSTR = 2048;   // flagd stride in ints = 8 KB
constexpr int ESLOT = 2 * NB * HHD;     // enc per-step slot (elems)
constexpr int DSLOT = NLAY * NB * HD;   // dec per-step slot (elems)

__device__ __forceinline__ float b2f(bf16 x) { return __bfloat162float(x); }
__device__ __forceinline__ bf16  f2b(float x) { return __float2bfloat16(x); }
__device__ __forceinline__ float sigm(float x) { return 1.0f / (1.0f + expf(-x)); }

__device__ __forceinline__ f32x4 mfma(bf16x8 a, bf16x8 b, f32x4 c) {
    return __builtin_amdgcn_mfma_f32_16x16x32_bf16(a, b, c, 0, 0, 0);
}
__device__ __forceinline__ f32x4 mfma3(bf16x8 ah, bf16x8 al, bf16x8 bh, bf16x8 bl, f32x4 c) {
    c = mfma(ah, bh, c);
    c = mfma(ah, bl, c);
    c = mfma(al, bh, c);
    return c;
}
__device__ __forceinline__ bf16x8 ld8(const bf16* p) { return *(const bf16x8*)p; }

// async global->LDS, 16B per lane; LDS base wave-uniform
__device__ __forceinline__ void g2l16(const void* g, void* l) {
    __builtin_amdgcn_global_load_lds(
        (const __attribute__((address_space(1))) unsigned int*)g,
        (__attribute__((address_space(3))) unsigned int*)l,
        16, 0, 0);
}

// ---- coherent (agent/L3) helpers (dec intra-launch PART handoff only) ----
__device__ __forceinline__ f32x4 ldc4f(const float* p) {
    union { f32x4 v; u64 q[2]; } u;
    u.q[0] = __hip_atomic_load((const u64*)p,     __ATOMIC_RELAXED, __HIP_MEMORY_SCOPE_AGENT);
    u.q[1] = __hip_atomic_load((const u64*)p + 1, __ATOMIC_RELAXED, __HIP_MEMORY_SCOPE_AGENT);
    return u.v;
}
__device__ __forceinline__ void stc4f(float* p, f32x4 v) {
    union { f32x4 v; u64 q[2]; } u;
    u.v = v;
    __hip_atomic_store((u64*)p,     u.q[0], __ATOMIC_RELAXED, __HIP_MEMORY_SCOPE_AGENT);
    __hip_atomic_store((u64*)p + 1, u.q[1], __ATOMIC_RELAXED, __HIP_MEMORY_SCOPE_AGENT);
}

// =====================================================================
// GEMM: C[m,n] = sum_k A[m,k]*W[n,k] (+bias)(opt tanh).
// A = hi/lo bf16 pair (g2l16-staged); W = fp32 -> bf16 (in-register).
// 2 MFMA per fragment. OM: 0 -> fp32 C; 1 -> bf16 hi/lo pair C.
// =====================================================================
template<int BM, bool BIAS, bool TANH, int OM>
__global__ __launch_bounds__(256) void gemmWf_k(
    const bf16* __restrict__ Ahi, const bf16* __restrict__ Alo,
    int64_t lda, int64_t sA,
    const float* __restrict__ W, int64_t ldw, int64_t sW,
    float* __restrict__ C, bf16* __restrict__ Chi, bf16* __restrict__ Clo,
    int64_t ldc, int64_t sC,
    const float* __restrict__ bias, int64_t sBias,
    int K)
{
    constexpr int FM = BM / 32;
    __shared__ __align__(16) bf16 Ah[BM * 32], Al[BM * 32];
    __shared__ __align__(16) bf16 Wl[128 * 32];
    const int z    = blockIdx.z;
    const bf16* Abh = Ahi + (int64_t)z * sA;
    const bf16* Abl = Alo + (int64_t)z * sA;
    const float* Wb = W + (int64_t)z * sW;
    const int n0   = blockIdx.x * 128;
    const int m0   = blockIdx.y * BM;
    const int tid  = threadIdx.x;
    const int lane = tid & 63, wid = tid >> 6;
    const int wm   = wid >> 1, wn = wid & 1;
    const int srow = lane >> 2;
    const int skb  = (lane & 3) * 8;
    const int r16  = lane & 15;
    const int k8   = (lane >> 4) * 8;

    f32x4 acc[FM][4];
    #pragma unroll
    for (int i = 0; i < FM; i++)
        #pragma unroll
        for (int j = 0; j < 4; j++)
            acc[i][j] = f32x4{0.f, 0.f, 0.f, 0.f};

    for (int k0 = 0; k0 < K; k0 += 32) {
        for (int c = wid; c < BM / 16; c += 4) {
            g2l16(Abh + (int64_t)(m0 + c * 16 + srow) * lda + k0 + skb, Ah + c * 512);
            g2l16(Abl + (int64_t)(m0 + c * 16 + srow) * lda + k0 + skb, Al + c * 512);
        }
        for (int c = wid; c < 8; c += 4) {
            const float* wp = Wb + (int64_t)(n0 + c * 16 + srow) * ldw + k0 + skb;
            bf16x8 wv;
            #pragma unroll
            for (int jj = 0; jj < 8; jj++) ((bf16*)&wv)[jj] = f2b(wp[jj]);
            *(bf16x8*)(Wl + c * 512 + lane * 8) = wv;
        }
        __syncthreads();
        bf16x8 afh[FM], afl[FM], wf[4];
        #pragma unroll
        for (int mt = 0; mt < FM; mt++) {
            const int off = (wm * (BM / 2) + mt * 16 + r16) * 32 + k8;
            afh[mt] = ld8(Ah + off);
            afl[mt] = ld8(Al + off);
        }
        #pragma unroll
        for (int nt = 0; nt < 4; nt++)
            wf[nt] = ld8(Wl + (wn * 64 + nt * 16 + r16) * 32 + k8);
        #pragma unroll
        for (int mt = 0; mt < FM; mt++)
            #pragma unroll
            for (int nt = 0; nt < 4; nt++) {
                acc[mt][nt] = mfma(afh[mt], wf[nt], acc[mt][nt]);
                acc[mt][nt] = mfma(afl[mt], wf[nt], acc[mt][nt]);
            }
        __syncthreads();
    }
    #pragma unroll
    for (int nt = 0; nt < 4; nt++) {
        const int n = n0 + wn * 64 + nt * 16 + r16;
        float bv = 0.f;
        if constexpr (BIAS) bv = bias[(int64_t)z * sBias + n];
        #pragma unroll
        for (int mt = 0; mt < FM; mt++) {
            const int mb = m0 + wm * (BM / 2) + mt * 16 + (lane >> 4) * 4;
            #pragma unroll
            for (int r = 0; r < 4; r++) {
                float v = acc[mt][nt][r] + bv;
                if constexpr (TANH) v = tanhf(v);
                const int64_t co = (int64_t)z * sC + (int64_t)(mb + r) * ldc + n;
                if constexpr (OM == 0) {
                    C[co] = v;
                } else {
                    bf16 hh = f2b(v);
                    Chi[co] = hh;
                    Clo[co] = f2b(v - b2f(hh));
                }
            }
        }
    }
}

__global__ void presplit_k(const float* __restrict__ x, bf16* __restrict__ hi,
                           bf16* __restrict__ lo, int n)
{
    const int i = blockIdx.x * 256 + threadIdx.x;
    if (i < n) {
        float v = x[i];
        bf16 h = f2b(v);
        hi[i] = h;
        lo[i] = f2b(v - b2f(h));
    }
}

// embed writing hi/lo pair
__global__ void embed2_k(const int* __restrict__ toks, const float* __restrict__ tab,
                         bf16* __restrict__ ohi, bf16* __restrict__ olo, int shifted)
{
    const int row = blockIdx.x;
    int tok;
    if (shifted) {
        const int t = row / NB, b = row - t * NB;
        tok = (t == 0) ? SOST : toks[(t - 1) * NB + b];
    } else {
        tok = toks[row];
    }
    const float4 v = ((const float4*)(tab + (int64_t)tok * HD))[threadIdx.x];
    bf16 h0 = f2b(v.x), h1 = f2b(v.y), h2 = f2b(v.z), h3 = f2b(v.w);
    bf16 hv[4] = {h0, h1, h2, h3};
    bf16 lv[4] = {f2b(v.x - b2f(h0)), f2b(v.y - b2f(h1)),
                  f2b(v.z - b2f(h2)), f2b(v.w - b2f(h3))};
    *(uint2*)(ohi + (int64_t)row * HD + threadIdx.x * 4) = *(uint2*)hv;
    *(uint2*)(olo + (int64_t)row * HD + threadIdx.x * 4) = *(uint2*)lv;
}

// =====================================================================
// Encoder PER-STEP kernel. Launch s = 0..LI-1 per layer.
// Grid (HHD/16=32, 2 dirs) x 256 thr (4 waves, K-split 128/wave).
// Reads slot s (plain), writes slot s+1 / Y / dh (plain). No atomics.
// =====================================================================
__global__ __launch_bounds__(256) void enc_step_k(
    const float* __restrict__ gi,     // [2][LI*NB][3*HHD] (+b_ih)
    const bf16* __restrict__ whhHi,   // this layer, [2][3*HHD][HHD]
    const bf16* __restrict__ whhLo,
    const float* __restrict__ bhh,    // [2][3*HHD]
    float* __restrict__ h32,          // [2 par][2 dir][NB][HHD]
    bf16* __restrict__ hsHi, bf16* __restrict__ hsLo,   // [LI][2][NB][HHD]
    bf16* __restrict__ yHi, bf16* __restrict__ yLo,
    float* __restrict__ dh32, bf16* __restrict__ dhHi, bf16* __restrict__ dhLo,
    int s)
{
    __shared__ f32x4 red[4][6][64];
    const int d = blockIdx.y;
    const int j0 = blockIdx.x * 16;
    const int tid = threadIdx.x;
    const int lane = tid & 63, wid = tid >> 6;
    const int r16 = lane & 15, k8 = (lane >> 4) * 8;
    const int kq = wid * 128;
    const bf16* WdH = whhHi + (int64_t)d * 3 * HHD * HHD;
    const bf16* WdL = whhLo + (int64_t)d * 3 * HHD * HHD;
    const int j = j0 + r16;
    const int t = d ? (LI - 1 - s) : s;
    const int par = s & 1, npar = par ^ 1;

    bf16x8 wh[3][4], wl[3][4];
    #pragma unroll
    for (int g = 0; g < 3; g++)
        #pragma unroll
        for (int kk = 0; kk < 4; kk++) {
            const int64_t wo = (int64_t)(g * HHD + j0 + r16) * HHD + kq + kk * 32 + k8;
            wh[g][kk] = ld8(WdH + wo);
            wl[g][kk] = ld8(WdL + wo);
        }

    const bf16* rH = hsHi + (size_t)s * ESLOT + (size_t)d * NB * HHD;
    const bf16* rL = hsLo + (size_t)s * ESLOT + (size_t)d * NB * HHD;

    f32x4 acc[2][3];
    #pragma unroll
    for (int m = 0; m < 2; m++)
        #pragma unroll
        for (int g = 0; g < 3; g++) acc[m][g] = f32x4{0.f, 0.f, 0.f, 0.f};

    #pragma unroll
    for (int kk = 0; kk < 4; kk++) {
        const int o0 = r16 * HHD + kq + kk * 32 + k8;
        const int o1 = (16 + r16) * HHD + kq + kk * 32 + k8;
        bf16x8 a0h = ld8(rH + o0), a0l = ld8(rL + o0);
        bf16x8 a1h = ld8(rH + o1), a1l = ld8(rL + o1);
        #pragma unroll
        for (int g = 0; g < 3; g++) {
            acc[0][g] = mfma3(a0h, a0l, wh[g][kk], wl[g][kk], acc[0][g]);
            acc[1][g] = mfma3(a1h, a1l, wh[g][kk], wl[g][kk], acc[1][g]);
        }
    }
    #pragma unroll
    for (int m = 0; m < 2; m++)
        #pragma unroll
        for (int g = 0; g < 3; g++)
            red[wid][m * 3 + g][lane] = acc[m][g];
    __syncthreads();
    if (wid == 0) {
        const float br = bhh[d * 3 * HHD + j];
        const float bz = bhh[d * 3 * HHD + HHD + j];
        const float bn = bhh[d * 3 * HHD + 2 * HHD + j];
        f32x4 a2[2][3];
        #pragma unroll
        for (int m = 0; m < 2; m++)
            #pragma unroll
            for (int g = 0; g < 3; g++)
                a2[m][g] = red[0][m * 3 + g][lane] + red[1][m * 3 + g][lane]
                         + red[2][m * 3 + g][lane] + red[3][m * 3 + g][lane];
        const float* gid = gi + ((int64_t)d * LI * NB + (int64_t)t * NB) * (3 * HHD);
        bf16* wH = hsHi + (size_t)(s + 1) * ESLOT + (size_t)d * NB * HHD;
        bf16* wL = hsLo + (size_t)(s + 1) * ESLOT + (size_t)d * NB * HHD;
        const int64_t hbase = (int64_t)(par * 2 + d) * NB * HHD;
        #pragma unroll
        for (int mt = 0; mt < 2; mt++)
            #pragma unroll
            for (int r = 0; r < 4; r++) {
                const int b = mt * 16 + (lane >> 4) * 4 + r;
                const float ir  = gid[b * 3 * HHD + j];
                const float iz  = gid[b * 3 * HHD + HHD + j];
                const float inn = gid[b * 3 * HHD + 2 * HHD + j];
                const float rg = sigm(ir + a2[mt][0][r] + br);
                const float zg = sigm(iz + a2[mt][1][r] + bz);
                const float ng = tanhf(inn + rg * (a2[mt][2][r] + bn));
                const float hold = h32[hbase + (int64_t)b * HHD + j];
                const float hnew = (1.f - zg) * ng + zg * hold;
                bf16 hh = f2b(hnew);
                bf16 hl = f2b(hnew - b2f(hh));
                h32[(int64_t)(npar * 2 + d) * NB * HHD + (int64_t)b * HHD + j] = hnew;
                const int lo_ = b * HHD + j;
                if (s < LI - 1) {
                    wH[lo_] = hh;
                    wL[lo_] = hl;
                }
                const int64_t yo = ((int64_t)t * NB + b) * HD + d * HHD + j;
                yHi[yo] = hh;
                yLo[yo] = hl;
                if (s == LI - 1) {
                    const int64_t dof = (int64_t)b * HD + d * HHD + j;
                    dh32[dof] = hnew;
                    dhHi[dof] = hh;
                    dhLo[dof] = hl;
                }
            }
    }
}

// =====================================================================
// Decoder PER-STEP kernel (round-14, passing/unchanged).
// =====================================================================
__global__ __launch_bounds__(512) void dec_step_k(
    const float* __restrict__ gi0,
    const bf16* __restrict__ wih1Hi, const bf16* __restrict__ wih1Lo,
    const bf16* __restrict__ whh0Hi, const bf16* __restrict__ whh0Lo,
    const bf16* __restrict__ whh1Hi, const bf16* __restrict__ whh1Lo,
    const float* __restrict__ bih1,
    const float* __restrict__ bhh0,
    const float* __restrict__ bhh1,
    float* __restrict__ h32,
    bf16* __restrict__ hsHi, bf16* __restrict__ hsLo,
    bf16* __restrict__ rnnHi, bf16* __restrict__ rnnLo,
    f32x4* __restrict__ part,
    int* __restrict__ flagd,
    int s)
{
    __shared__ f32x4 red[8][8][64];
    const int tid = threadIdx.x;
    const int lane = tid & 63, wid = tid >> 6;
    const int r16 = lane & 15, k8 = (lane >> 4) * 8;
    const int j0 = blockIdx.x * 16;
    const int j = j0 + r16;

    if (blockIdx.y == 0) {
        if (s >= LO) return;
        const int t = s, par = t & 1, npar = par ^ 1;
        const int kq = wid * 128;
        bf16x8 wh[3][4], wl[3][4];
        #pragma unroll
        for (int g = 0; g < 3; g++)
            #pragma unroll
            for (int kk = 0; kk < 4; kk++) {
                const int64_t wo = (int64_t)(g * HD + j0 + r16) * HD + kq + kk * 32 + k8;
                wh[g][kk] = ld8(whh0Hi + wo);
                wl[g][kk] = ld8(whh0Lo + wo);
            }
        const bf16* rH = hsHi + (size_t)s * DSLOT;
        const bf16* rL = hsLo + (size_t)s * DSLOT;
        f32x4 acc[2][3];
        #pragma unroll
        for (int m = 0; m < 2; m++)
            #pragma unroll
            for (int g = 0; g < 3; g++) acc[m][g] = f32x4{0.f, 0.f, 0.f, 0.f};
        #pragma unroll
        for (int kk = 0; kk < 4; kk++) {
            const int o0 = r16 * HD + kq + kk * 32 + k8;
            const int o1 = (16 + r16) * HD + kq + kk * 32 + k8;
            bf16x8 a0h = ld8(rH + o0), a0l = ld8(rL + o0);
            bf16x8 a1h = ld8(rH + o1), a1l = ld8(rL + o1);
            #pragma unroll
            for (int g = 0; g < 3; g++) {
                acc[0][g] = mfma3(a0h, a0l, wh[g][kk], wl[g][kk], acc[0][g]);
                acc[1][g] = mfma3(a1h, a1l, wh[g][kk], wl[g][kk], acc[1][g]);
            }
        }
        #pragma unroll
        for (int m = 0; m < 2; m++)
            #pragma unroll
            for (int g = 0; g < 3; g++)
                red[wid][m * 3 + g][lane] = acc[m][g];
        __syncthreads();
        if (wid == 0) {
            const float b0r = bhh0[j], b0z = bhh0[HD + j], b0n = bhh0[2 * HD + j];
            f32x4 a2[2][3];
            #pragma unroll
            for (int m = 0; m < 2; m++)
                #pragma unroll
                for (int g = 0; g < 3; g++) {
                    f32x4 v = red[0][m * 3 + g][lane];
                    #pragma unroll
                    for (int w2 = 1; w2 < 8; w2++) v += red[w2][m * 3 + g][lane];
                    a2[m][g] = v;
                }
            const float* gid = gi0 + (int64_t)t * NB * 3 * HD;
            bf16* wHs = hsHi + (size_t)(s + 1) * DSLOT;
            bf16* wLs = hsLo + (size_t)(s + 1) * DSLOT;
            const int64_t hb = (int64_t)(par * NLAY + 0) * NB * HD;
            #pragma unroll
            for (int mt = 0; mt < 2; mt++)
                #pragma unroll
                for (int r = 0; r < 4; r++) {
                    const int b = mt * 16 + (lane >> 4) * 4 + r;
                    const float ir  = gid[b * 3 * HD + j];
                    const float iz  = gid[b * 3 * HD + HD + j];
                    const float inn = gid[b * 3 * HD + 2 * HD + j];
                    const float rg = sigm(ir + a2[mt][0][r] + b0r);
                    const float zg = sigm(iz + a2[mt][1][r] + b0z);
                    const float ng = tanhf(inn + rg * (a2[mt][2][r] + b0n));
                    const float hold = h32[hb + (int64_t)b * HD + j];
                    const float hnew = (1.f - zg) * ng + zg * hold;
                    bf16 hh = f2b(hnew);
                    bf16 hl = f2b(hnew - b2f(hh));
                    h32[(int64_t)(npar * NLAY + 0) * NB * HD + (int64_t)b * HD + j] = hnew;
                    const int lo_ = b * HD + j;
                    wHs[lo_] = hh;
                    wLs[lo_] = hl;
                }
        }
    } else {
        if (s < 1) return;
        const int t = s - 1;
        const int p1 = t & 1, np1 = p1 ^ 1;
        const int kh = blockIdx.y - 1;
        const int kb = kh * 512 + wid * 64;
        bf16x8 wIh[3][2], wIl[3][2], wHh[3][2], wHl[3][2];
        #pragma unroll
        for (int g = 0; g < 3; g++)
            #pragma unroll
            for (int kk = 0; kk < 2; kk++) {
                const int64_t wo = (int64_t)(g * HD + j0 + r16) * HD + kb + kk * 32 + k8;
                wIh[g][kk] = ld8(wih1Hi + wo);
                wIl[g][kk] = ld8(wih1Lo + wo);
                wHh[g][kk] = ld8(whh1Hi + wo);
                wHl[g][kk] = ld8(whh1Lo + wo);
            }
        const bf16* xH = hsHi + (size_t)s * DSLOT;
        const bf16* xL = hsLo + (size_t)s * DSLOT;
        const bf16* yH = hsHi + (size_t)(s - 1) * DSLOT + (size_t)NB * HD;
        const bf16* yL = hsLo + (size_t)(s - 1) * DSLOT + (size_t)NB * HD;
        f32x4 arz[2][2], ain[2], ahn[2];
        #pragma unroll
        for (int i = 0; i < 2; i++) {
            arz[i][0] = f32x4{0.f, 0.f, 0.f, 0.f};
            arz[i][1] = f32x4{0.f, 0.f, 0.f, 0.f};
            ain[i] = f32x4{0.f, 0.f, 0.f, 0.f};
            ahn[i] = f32x4{0.f, 0.f, 0.f, 0.f};
        }
        #pragma unroll
        for (int kk = 0; kk < 2; kk++) {
            const int o0 = r16 * HD + kb + kk * 32 + k8;
            const int o1 = (16 + r16) * HD + kb + kk * 32 + k8;
            bf16x8 x0h = ld8(xH + o0), x0l = ld8(xL + o0);
            bf16x8 x1h = ld8(xH + o1), x1l = ld8(xL + o1);
            bf16x8 y0h = ld8(yH + o0), y0l = ld8(yL + o0);
            bf16x8 y1h = ld8(yH + o1), y1l = ld8(yL + o1);
            arz[0][0] = mfma3(x0h, x0l, wIh[0][kk], wIl[0][kk], arz[0][0]);
            arz[0][0] = mfma3(y0h, y0l, wHh[0][kk], wHl[0][kk], arz[0][0]);
            arz[1][0] = mfma3(x1h, x1l, wIh[0][kk], wIl[0][kk], arz[1][0]);
            arz[1][0] = mfma3(y1h, y1l, wHh[0][kk], wHl[0][kk], arz[1][0]);
            arz[0][1] = mfma3(x0h, x0l, wIh[1][kk], wIl[1][kk], arz[0][1]);
            arz[0][1] = mfma3(y0h, y0l, wHh[1][kk], wHl[1][kk], arz[0][1]);
            arz[1][1] = mfma3(x1h, x1l, wIh[1][kk], wIl[1][kk], arz[1][1]);
            arz[1][1] = mfma3(y1h, y1l, wHh[1][kk], wHl[1][kk], arz[1][1]);
            ain[0] = mfma3(x0h, x0l, wIh[2][kk], wIl[2][kk], ain[0]);
            ain[1] = mfma3(x1h, x1l, wIh[2][kk], wIl[2][kk], ain[1]);
            ahn[0] = mfma3(y0h, y0l, wHh[2][kk], wHl[2][kk], ahn[0]);
            ahn[1] = mfma3(y1h, y1l, wHh[2][kk], wHl[2][kk], ahn[1]);
        }
        red[wid][0][lane] = arz[0][0];
        red[wid][1][lane] = arz[1][0];
        red[wid][2][lane] = arz[0][1];
        red[wid][3][lane] = arz[1][1];
        red[wid][4][lane] = ain[0];
        red[wid][5][lane] = ain[1];
        red[wid][6][lane] = ahn[0];
        red[wid][7][lane] = ahn[1];
        __syncthreads();
        if (wid == 0) {
            f32x4 p[8];
            #pragma unroll
            for (int grp = 0; grp < 8; grp++) {
                f32x4 v = red[0][grp][lane];
                #pragma unroll
                for (int w2 = 1; w2 < 8; w2++) v += red[w2][grp][lane];
                p[grp] = v;
            }
            if (kh == 1) {
                #pragma unroll
                for (int grp = 0; grp < 8; grp++)
                    stc4f((float*)&part[((size_t)blockIdx.x * 8 + grp) * 64 + lane], p[grp]);
                asm volatile("s_waitcnt vmcnt(0)" ::: "memory");
                if (lane == 0)
                    __hip_atomic_store(&flagd[blockIdx.x * BSTR], s, __ATOMIC_RELAXED, __HIP_MEMORY_SCOPE_AGENT);
            } else {
                while (__hip_atomic_load(&flagd[blockIdx.x * BSTR], __ATOMIC_RELAXED, __HIP_MEMORY_SCOPE_AGENT) < s)
                    __builtin_amdgcn_s_sleep(1);
                asm volatile("" ::: "memory");
                #pragma unroll
                for (int grp = 0; grp < 8; grp++)
                    p[grp] += ldc4f((const float*)&part[((size_t)blockIdx.x * 8 + grp) * 64 + lane]);
                const float brr = bih1[j] + bhh1[j];
                const float bzz = bih1[HD + j] + bhh1[HD + j];
                const float bin = bih1[2 * HD + j];
                const float bhn = bhh1[2 * HD + j];
                bf16* wHs = hsHi + (size_t)s * DSLOT + (size_t)NB * HD;
                bf16* wLs = hsLo + (size_t)s * DSLOT + (size_t)NB * HD;
                const int64_t h1b = (int64_t)(p1 * NLAY + 1) * NB * HD;
                #pragma unroll
                for (int mt = 0; mt < 2; mt++)
                    #pragma unroll
                    for (int r = 0; r < 4; r++) {
                        const int b = mt * 16 + (lane >> 4) * 4 + r;
                        const float rg = sigm(p[0 + mt][r] + brr);
                        const float zg = sigm(p[2 + mt][r] + bzz);
                        const float ng = tanhf(p[4 + mt][r] + bin + rg * (p[6 + mt][r] + bhn));
                        const float hold = h32[h1b + (int64_t)b * HD + j];
                        const float hnew = (1.f - zg) * ng + zg * hold;
                        bf16 hh = f2b(hnew);
                        bf16 hl = f2b(hnew - b2f(hh));
                        h32[(int64_t)(np1 * NLAY + 1) * NB * HD + (int64_t)b * HD + j] = hnew;
                        const int lo_ = b * HD + j;
                        wHs[lo_] = hh;
                        wLs[lo_] = hl;
                        const int64_t ro = ((int64_t)t * NB + b) * HD + j;
                        rnnHi[ro] = hh;
                        rnnLo[ro] = hl;
                    }
            }
        }
    }
}

// =====================================================================
__global__ __launch_bounds__(64) void softmax_k(const float* __restrict__ sc,
                                                float* __restrict__ aout)
{
    const int row = blockIdx.x, l = threadIdx.x;
    float v0 = sc[row * LI + l], v1 = sc[row * LI + 64 + l];
    float m = fmaxf(v0, v1);
    #pragma unroll
    for (int o = 32; o > 0; o >>= 1) m = fmaxf(m, __shfl_xor(m, o));
    float e0 = expf(v0 - m), e1 = expf(v1 - m);
    float s = e0 + e1;
    #pragma unroll
    for (int o = 32; o > 0; o >>= 1) s += __shfl_xor(s, o);
    const float inv = 1.f / s;
    aout[row * LI + l] = e0 * inv;
    aout[row * LI + 64 + l] = e1 * inv;
}

// ctx from hi/lo enc outputs -> hi/lo JIN
__global__ __launch_bounds__(256) void ctx2_k(const float* __restrict__ at,
                                              const bf16* __restrict__ eHi,
                                              const bf16* __restrict__ eLo,
                                              bf16* __restrict__ jHi,
                                              bf16* __restrict__ jLo)
{
    const int b = blockIdx.y, h0 = blockIdx.x * 128;
    __shared__ __align__(16) float al[LO][LI];
    for (int i = threadIdx.x; i < LO * LI; i += 256) {
        const int to = i >> 7, ti = i & 127;
        al[to][ti] = at[(to * NB + b) * LI + ti];
    }
    __syncthreads();
    const int hc = h0 + (threadIdx.x & 127);
    const int rh = threadIdx.x >> 7;
    float acc[32];
    #pragma unroll
    for (int i = 0; i < 32; i++) acc[i] = 0.f;
    for (int t = 0; t < LI; t++) {
        const int64_t eo = ((int64_t)t * NB + b) * HD + hc;
        const float ev = b2f(eHi[eo]) + b2f(eLo[eo]);
        #pragma unroll
        for (int i = 0; i < 32; i++) acc[i] += ev * al[rh * 32 + i][t];
    }
    #pragma unroll
    for (int i = 0; i < 32; i++) {
        const int64_t jo = ((int64_t)(rh * 32 + i) * NB + b) * (2 * HD) + hc;
        bf16 hh = f2b(acc[i]);
        jHi[jo] = hh;
        jLo[jo] = f2b(acc[i] - b2f(hh));
    }
}

// copy RNN hi/lo into JIN[:, HD:2HD]
__global__ void rnncopy2_k(const bf16* __restrict__ rHi, const bf16* __restrict__ rLo,
                           bf16* __restrict__ jHi, bf16* __restrict__ jLo)
{
    const int idx = blockIdx.x * 256 + threadIdx.x;
    const int row = idx >> 8;
    const int c = idx & 255;
    ((uint2*)jHi)[(int64_t)row * 512 + 256 + c] = ((const uint2*)rHi)[idx];
    ((uint2*)jLo)[(int64_t)row * 512 + 256 + c] = ((const uint2*)rLo)[idx];
}

// =====================================================================
extern "C" void kernel_launch(void* const* d_in, const int* in_sizes, int n_in,
                              void* d_out, int out_size, void* d_ws, size_t ws_size,
                              hipStream_t stream)
{
    (void)in_sizes; (void)n_in; (void)out_size; (void)ws_size;
    const int*   in_tok   = (const int*)d_in[0];
    const int*   out_tok  = (const int*)d_in[2];
    const float* enc_emb  = (const float*)d_in[4];
    const float* enc_wih  = (const float*)d_in[5];
    const float* enc_whh  = (const float*)d_in[6];
    const float* enc_bih  = (const float*)d_in[7];
    const float* enc_bhh  = (const float*)d_in[8];
    const float* dec_emb  = (const float*)d_in[9];
    const float* dec_wih  = (const float*)d_in[10];
    const float* dec_whh  = (const float*)d_in[11];
    const float* dec_bih  = (const float*)d_in[12];
    const float* dec_bhh  = (const float*)d_in[13];
    const float* attn_W   = (const float*)d_in[14];
    const float* joiner_W = (const float*)d_in[15];
    const float* joiner_b = (const float*)d_in[16];
    const float* proj_W   = (const float*)d_in[17];
    const float* proj_b   = (const float*)d_in[18];
    float* logits   = (float*)d_out;
    float* attn_out = logits + (size_t)LO * NB * NV;

    const size_t MB = 1ull << 20;
    char* o = (char*)d_out;   // logits region = 250 MiB fp32
    bf16* XB0HI  = (bf16*)(o);               // 8 MiB (dead after L0 gi)
    bf16* XB0LO  = (bf16*)(o + 8 * MB);      // 8 MiB
    bf16* XB1HI  = (bf16*)(o + 16 * MB);     // 8 MiB
    bf16* XB1LO  = (bf16*)(o + 24 * MB);     // 8 MiB
    bf16* EOUTHI = (bf16*)(o + 32 * MB);     // 8 MiB (alive until ctx)
    bf16* EOUTLO = (bf16*)(o + 40 * MB);     // 8 MiB
    float* PENC  = (float*)(o + 48 * MB);    // 16 MiB fp32
    float* GI    = (float*)(o + 64 * MB);    // 48 MiB fp32
    float* DGI0  = (float*)(o + 112 * MB);   // 24 MiB fp32
    bf16* ENCH_HI = (bf16*)(o + 136 * MB);   // 8 MiB per-step slots
    bf16* ENCH_LO = (bf16*)(o + 144 * MB);   // 8 MiB
    bf16* JINHI  = (bf16*)(o + 152 * MB);    // 8 MiB (written post-dec)
    bf16* JINLO  = (bf16*)(o + 160 * MB);    // 8 MiB
    bf16* RNNHI  = (bf16*)(o + 168 * MB);    // 4 MiB
    bf16* RNNLO  = (bf16*)(o + 172 * MB);    // 4 MiB
    float* SC    = (float*)(o + 176 * MB);   // 1 MiB
    bf16* WencHi = (bf16*)(o + 177 * MB);    // 6 MiB
    bf16* WencLo = (bf16*)(o + 183 * MB);    // 6 MiB
    bf16* WdhHi  = (bf16*)(o + 189 * MB);    // 12 MiB
    bf16* WdhLo  = (bf16*)(o + 201 * MB);    // 12 MiB
    bf16* Wih1Hi = (bf16*)(o + 213 * MB);    // 6 MiB
    bf16* Wih1Lo = (bf16*)(o + 219 * MB);    // 6 MiB
    char* ba     = o + 225 * MB;             // flagd arena (512 KiB used)
    f32x4* PART  = (f32x4*)(o + 228 * MB);   // 0.5 MiB
    bf16* DEMBHI = (bf16*)(o + 229 * MB);    // 4 MiB
    bf16* DEMBLO = (bf16*)(o + 233 * MB);    // 4 MiB -> ends 237 < 250
    bf16* DECH_HI = XB0HI;                   // dec per-step slots (XB0 dead)
    bf16* DECH_LO = JINHI;                   // (JIN written post-dec)

    char* w = (char*)d_ws;
    bf16* VECSHI = (bf16*)(w);                        // 4 MiB
    bf16* VECSLO = (bf16*)(w + 4 * MB);               // 4 MiB
    float* EH32  = (float*)(w + 8 * MB);              // 512 KiB
    float* DH32  = (float*)(w + 8 * MB + 524288);     // 512 KiB

    int* FLAGD = (int*)(ba);                 // 64 x 8KB = 512 KiB

    hipMemsetAsync(ba, 0, 512 * 1024, stream);
    hipMemsetAsync(ENCH_HI, 0, (size_t)ESLOT * 2, stream);   // enc slot 0 = zeros
    hipMemsetAsync(ENCH_LO, 0, (size_t)ESLOT * 2, stream);

    // ---- pre-split recurrent weights ----
    const int nEnc = NLAY * 2 * 3 * HHD * HHD;
    const int nDhh = NLAY * 3 * HD * HD;
    const int nIh1 = 3 * HD * HD;
    presplit_k<<<dim3((nEnc + 255) / 256), dim3(256), 0, stream>>>(enc_whh, WencHi, WencLo, nEnc);
    presplit_k<<<dim3((nDhh + 255) / 256), dim3(256), 0, stream>>>(dec_whh, WdhHi, WdhLo, nDhh);
    presplit_k<<<dim3((nIh1 + 255) / 256), dim3(256), 0, stream>>>(dec_wih + (size_t)3 * HD * HD, Wih1Hi, Wih1Lo, nIh1);

    // ---- decoder prep ----
    embed2_k<<<dim3(LO * NB), dim3(256), 0, stream>>>(out_tok, dec_emb, DEMBHI, DEMBLO, 1);
    gemmWf_k<128, true, false, 0><<<dim3(3 * HD / 128, LO * NB / 128, 1), 256, 0, stream>>>(
        DEMBHI, DEMBLO, HD, 0, dec_wih, HD, 0,
        DGI0, nullptr, nullptr, 3 * HD, 0, dec_bih, 0, HD);

    // ---- encoder: 2 layers x 128 per-step launches ----
    embed2_k<<<dim3(LI * NB), dim3(256), 0, stream>>>(in_tok, enc_emb, XB0HI, XB0LO, 0);
    for (int l = 0; l < NLAY; l++) {
        const bf16* XinH = l ? XB1HI : XB0HI;
        const bf16* XinL = l ? XB1LO : XB0LO;
        bf16* YoH = l ? EOUTHI : XB1HI;
        bf16* YoL = l ? EOUTLO : XB1LO;
        hipMemsetAsync(EH32, 0, (size_t)2 * 2 * NB * HHD * 4, stream);
        gemmWf_k<128, true, false, 0><<<dim3(3 * HHD / 128, LI * NB / 128, 2), 256, 0, stream>>>(
            XinH, XinL, HD, 0,
            enc_wih + (size_t)l * 2 * 3 * HHD * HD, HD, (int64_t)3 * HHD * HD,
            GI, nullptr, nullptr, 3 * HHD, (int64_t)LI * NB * 3 * HHD,
            enc_bih + l * 2 * 3 * HHD, 3 * HHD, HD);
        for (int s = 0; s < LI; s++)
            enc_step_k<<<dim3(HHD / 16, 2), dim3(256), 0, stream>>>(
                GI,
                WencHi + (size_t)l * 2 * 3 * HHD * HHD,
                WencLo + (size_t)l * 2 * 3 * HHD * HHD,
                enc_bhh + l * 2 * 3 * HHD,
                EH32, ENCH_HI, ENCH_LO, YoH, YoL,
                DH32 + (size_t)l * NB * HD,
                DECH_HI + (size_t)l * NB * HD,
                DECH_LO + (size_t)l * NB * HD,
                s);
    }

    // proj_enc = enc_outputs @ attn_W^T
    gemmWf_k<128, false, false, 0><<<dim3(HD / 128, LI * NB / 128, 1), 256, 0, stream>>>(
        EOUTHI, EOUTLO, HD, 0, attn_W, HD, 0,
        PENC, nullptr, nullptr, HD, 0, nullptr, 0, HD);

    // ---- decoder recurrence: 65 per-step launches ----
    for (int s = 0; s <= LO; s++)
        dec_step_k<<<dim3(HD / 16, 3), dim3(512), 0, stream>>>(
            DGI0,
            Wih1Hi, Wih1Lo,
            WdhHi, WdhLo,
            WdhHi + (size_t)3 * HD * HD, WdhLo + (size_t)3 * HD * HD,
            dec_bih + 3 * HD, dec_bhh, dec_bhh + 3 * HD,
            DH32, DECH_HI, DECH_LO, RNNHI, RNNLO, PART, FLAGD, s);

    // ---- batched epilogue ----
    gemmWf_k<64, false, false, 0><<<dim3(1, 1, NB), 256, 0, stream>>>(
        RNNHI, RNNLO, (int64_t)NB * HD, HD, PENC, (int64_t)NB * HD, HD,
        SC, nullptr, nullptr, (int64_t)NB * LI, LI, nullptr, 0, HD);
    softmax_k<<<dim3(LO * NB), dim3(64), 0, stream>>>(SC, attn_out);
    ctx2_k<<<dim3(HD / 128, NB), dim3(256), 0, stream>>>(attn_out, EOUTHI, EOUTLO, JINHI, JINLO);
    rnncopy2_k<<<dim3(LO * NB * HD / 4 / 256), dim3(256), 0, stream>>>(RNNHI, RNNLO, JINHI, JINLO);
    gemmWf_k<128, true, true, 1><<<dim3(HD / 128, LO * NB / 128, 1), 256, 0, stream>>>(
        JINHI, JINLO, 2 * HD, 0, joiner_W, 2 * HD, 0,
        nullptr, VECSHI, VECSLO, HD, 0, joiner_b, 0, 2 * HD);
    gemmWf_k<128, true, false, 0><<<dim3(NV / 128, LO * NB / 128, 1), 256, 0, stream>>>(
        VECSHI, VECSLO, HD, 0, proj_W, HD, 0,
        logits, nullptr, nullptr, NV, 0, proj_b, 0, HD);
}

// Round 17
// 4168.283 us; speedup vs baseline: 1.2950x; 1.2950x over previous
//
#include <hip/hip_runtime.h>
#include <hip/hip_bf16.h>
#include <stdint.h>

// ---- problem constants ----
constexpr int LI   = 128;    // L_IN
constexpr int LO   = 64;     // L_OUT
constexpr int NB   = 32;     // batch
constexpr int HD   = 1024;   // H
constexpr int HHD  = 512;    // HH
constexpr int NLAY = 2;
constexpr int NV   = 32000;  // V_OUT
constexpr int SOST = 1;

// Round-17: round-16 minus the PROJB self-race (logits GEMM read its bf16
// W from the region its own output overwrites -> random bf16-NaN patterns).
// bf16 proj_W now only if it fits in d_ws (guarded, written-before-read);
// else fp32 fallback (round-14 proven). gbarA + small bf16 W copies kept.

typedef __hip_bfloat16 bf16;
typedef __attribute__((ext_vector_type(8))) short bf16x8;
typedef __attribute__((ext_vector_type(4))) float f32x4;
typedef unsigned long long u64;

constexpr int BSTR = 2048;   // flag stride in ints = 8 KB
constexpr int ESLOT = 2 * NB * HHD;     // enc per-step slot (elems)
constexpr int DSLOT = NLAY * NB * HD;   // dec per-step slot (elems)

__device__ __forceinline__ float b2f(bf16 x) { return __bfloat162float(x); }
__device__ __forceinline__ bf16  f2b(float x) { return __float2bfloat16(x); }
__device__ __forceinline__ float sigm(float x) { return 1.0f / (1.0f + expf(-x)); }

__device__ __forceinline__ f32x4 mfma(bf16x8 a, bf16x8 b, f32x4 c) {
    return __builtin_amdgcn_mfma_f32_16x16x32_bf16(a, b, c, 0, 0, 0);
}
__device__ __forceinline__ f32x4 mfma3(bf16x8 ah, bf16x8 al, bf16x8 bh, bf16x8 bl, f32x4 c) {
    c = mfma(ah, bh, c);
    c = mfma(ah, bl, c);
    c = mfma(al, bh, c);
    return c;
}
__device__ __forceinline__ bf16x8 ld8(const bf16* p) { return *(const bf16x8*)p; }

// async global->LDS, 16B per lane; LDS base wave-uniform
__device__ __forceinline__ void g2l16(const void* g, void* l) {
    __builtin_amdgcn_global_load_lds(
        (const __attribute__((address_space(1))) unsigned int*)g,
        (__attribute__((address_space(3))) unsigned int*)l,
        16, 0, 0);
}

// ---- coherent (agent/L3) helpers ----
__device__ __forceinline__ void stc2(bf16* p, bf16 a, bf16 b) {
    unsigned v = (unsigned)*(const unsigned short*)&a |
                 ((unsigned)*(const unsigned short*)&b << 16);
    __hip_atomic_store((unsigned*)p, v, __ATOMIC_RELAXED, __HIP_MEMORY_SCOPE_AGENT);
}
__device__ __forceinline__ f32x4 ldc4f(const float* p) {
    union { f32x4 v; u64 q[2]; } u;
    u.q[0] = __hip_atomic_load((const u64*)p,     __ATOMIC_RELAXED, __HIP_MEMORY_SCOPE_AGENT);
    u.q[1] = __hip_atomic_load((const u64*)p + 1, __ATOMIC_RELAXED, __HIP_MEMORY_SCOPE_AGENT);
    return u.v;
}
__device__ __forceinline__ void stc4f(float* p, f32x4 v) {
    union { f32x4 v; u64 q[2]; } u;
    u.v = v;
    __hip_atomic_store((u64*)p,     u.q[0], __ATOMIC_RELAXED, __HIP_MEMORY_SCOPE_AGENT);
    __hip_atomic_store((u64*)p + 1, u.q[1], __ATOMIC_RELAXED, __HIP_MEMORY_SCOPE_AGENT);
}

// ---- all-to-all flag barrier: arrival = strided flag store; every
// block's wave0 polls all nblk flags, one per lane. No master/epoch.
__device__ __forceinline__ void gbarA(int* __restrict__ flags,
                                      int nblk, int myid, int val) {
    __syncthreads();
    const int tid = threadIdx.x;
    if (tid < 64) {
        if (tid == 0) {
            asm volatile("s_waitcnt vmcnt(0)" ::: "memory");
            __hip_atomic_store(&flags[myid * BSTR], val, __ATOMIC_RELAXED, __HIP_MEMORY_SCOPE_AGENT);
        }
        bool done = false;
        while (!done) {
            int v = (tid < nblk)
                ? __hip_atomic_load(&flags[tid * BSTR], __ATOMIC_RELAXED, __HIP_MEMORY_SCOPE_AGENT)
                : val;
            done = __all(v >= val);
            if (!done) __builtin_amdgcn_s_sleep(1);
        }
        asm volatile("" ::: "memory");
    }
    __syncthreads();
}

// =====================================================================
// GEMM (fp32 W, rounded to bf16 in-register).
// =====================================================================
template<int BM, bool BIAS, bool TANH, int OM>
__global__ __launch_bounds__(256) void gemmWf_k(
    const bf16* __restrict__ Ahi, const bf16* __restrict__ Alo,
    int64_t lda, int64_t sA,
    const float* __restrict__ W, int64_t ldw, int64_t sW,
    float* __restrict__ C, bf16* __restrict__ Chi, bf16* __restrict__ Clo,
    int64_t ldc, int64_t sC,
    const float* __restrict__ bias, int64_t sBias,
    int K)
{
    constexpr int FM = BM / 32;
    __shared__ __align__(16) bf16 Ah[BM * 32], Al[BM * 32];
    __shared__ __align__(16) bf16 Wl[128 * 32];
    const int z    = blockIdx.z;
    const bf16* Abh = Ahi + (int64_t)z * sA;
    const bf16* Abl = Alo + (int64_t)z * sA;
    const float* Wb = W + (int64_t)z * sW;
    const int n0   = blockIdx.x * 128;
    const int m0   = blockIdx.y * BM;
    const int tid  = threadIdx.x;
    const int lane = tid & 63, wid = tid >> 6;
    const int wm   = wid >> 1, wn = wid & 1;
    const int srow = lane >> 2;
    const int skb  = (lane & 3) * 8;
    const int r16  = lane & 15;
    const int k8   = (lane >> 4) * 8;

    f32x4 acc[FM][4];
    #pragma unroll
    for (int i = 0; i < FM; i++)
        #pragma unroll
        for (int j = 0; j < 4; j++)
            acc[i][j] = f32x4{0.f, 0.f, 0.f, 0.f};

    for (int k0 = 0; k0 < K; k0 += 32) {
        for (int c = wid; c < BM / 16; c += 4) {
            g2l16(Abh + (int64_t)(m0 + c * 16 + srow) * lda + k0 + skb, Ah + c * 512);
            g2l16(Abl + (int64_t)(m0 + c * 16 + srow) * lda + k0 + skb, Al + c * 512);
        }
        for (int c = wid; c < 8; c += 4) {
            const float* wp = Wb + (int64_t)(n0 + c * 16 + srow) * ldw + k0 + skb;
            bf16x8 wv;
            #pragma unroll
            for (int jj = 0; jj < 8; jj++) ((bf16*)&wv)[jj] = f2b(wp[jj]);
            *(bf16x8*)(Wl + c * 512 + lane * 8) = wv;
        }
        __syncthreads();
        bf16x8 afh[FM], afl[FM], wf[4];
        #pragma unroll
        for (int mt = 0; mt < FM; mt++) {
            const int off = (wm * (BM / 2) + mt * 16 + r16) * 32 + k8;
            afh[mt] = ld8(Ah + off);
            afl[mt] = ld8(Al + off);
        }
        #pragma unroll
        for (int nt = 0; nt < 4; nt++)
            wf[nt] = ld8(Wl + (wn * 64 + nt * 16 + r16) * 32 + k8);
        #pragma unroll
        for (int mt = 0; mt < FM; mt++)
            #pragma unroll
            for (int nt = 0; nt < 4; nt++) {
                acc[mt][nt] = mfma(afh[mt], wf[nt], acc[mt][nt]);
                acc[mt][nt] = mfma(afl[mt], wf[nt], acc[mt][nt]);
            }
        __syncthreads();
    }
    #pragma unroll
    for (int nt = 0; nt < 4; nt++) {
        const int n = n0 + wn * 64 + nt * 16 + r16;
        float bv = 0.f;
        if constexpr (BIAS) bv = bias[(int64_t)z * sBias + n];
        #pragma unroll
        for (int mt = 0; mt < FM; mt++) {
            const int mb = m0 + wm * (BM / 2) + mt * 16 + (lane >> 4) * 4;
            #pragma unroll
            for (int r = 0; r < 4; r++) {
                float v = acc[mt][nt][r] + bv;
                if constexpr (TANH) v = tanhf(v);
                const int64_t co = (int64_t)z * sC + (int64_t)(mb + r) * ldc + n;
                if constexpr (OM == 0) {
                    C[co] = v;
                } else {
                    bf16 hh = f2b(v);
                    Chi[co] = hh;
                    Clo[co] = f2b(v - b2f(hh));
                }
            }
        }
    }
}

// =====================================================================
// GEMM with PRE-SPLIT bf16 W (g2l16-staged). Numerically identical.
// =====================================================================
template<int BM, bool BIAS, bool TANH, int OM>
__global__ __launch_bounds__(256) void gemmBW_k(
    const bf16* __restrict__ Ahi, const bf16* __restrict__ Alo,
    int64_t lda, int64_t sA,
    const bf16* __restrict__ W, int64_t ldw, int64_t sW,
    float* __restrict__ C, bf16* __restrict__ Chi, bf16* __restrict__ Clo,
    int64_t ldc, int64_t sC,
    const float* __restrict__ bias, int64_t sBias,
    int K)
{
    constexpr int FM = BM / 32;
    __shared__ __align__(16) bf16 Ah[BM * 32], Al[BM * 32];
    __shared__ __align__(16) bf16 Wl[128 * 32];
    const int z    = blockIdx.z;
    const bf16* Abh = Ahi + (int64_t)z * sA;
    const bf16* Abl = Alo + (int64_t)z * sA;
    const bf16* Wb = W + (int64_t)z * sW;
    const int n0   = blockIdx.x * 128;
    const int m0   = blockIdx.y * BM;
    const int tid  = threadIdx.x;
    const int lane = tid & 63, wid = tid >> 6;
    const int wm   = wid >> 1, wn = wid & 1;
    const int srow = lane >> 2;
    const int skb  = (lane & 3) * 8;
    const int r16  = lane & 15;
    const int k8   = (lane >> 4) * 8;

    f32x4 acc[FM][4];
    #pragma unroll
    for (int i = 0; i < FM; i++)
        #pragma unroll
        for (int j = 0; j < 4; j++)
            acc[i][j] = f32x4{0.f, 0.f, 0.f, 0.f};

    for (int k0 = 0; k0 < K; k0 += 32) {
        for (int c = wid; c < BM / 16; c += 4) {
            g2l16(Abh + (int64_t)(m0 + c * 16 + srow) * lda + k0 + skb, Ah + c * 512);
            g2l16(Abl + (int64_t)(m0 + c * 16 + srow) * lda + k0 + skb, Al + c * 512);
        }
        for (int c = wid; c < 8; c += 4)
            g2l16(Wb + (int64_t)(n0 + c * 16 + srow) * ldw + k0 + skb, Wl + c * 512);
        __syncthreads();
        bf16x8 afh[FM], afl[FM], wf[4];
        #pragma unroll
        for (int mt = 0; mt < FM; mt++) {
            const int off = (wm * (BM / 2) + mt * 16 + r16) * 32 + k8;
            afh[mt] = ld8(Ah + off);
            afl[mt] = ld8(Al + off);
        }
        #pragma unroll
        for (int nt = 0; nt < 4; nt++)
            wf[nt] = ld8(Wl + (wn * 64 + nt * 16 + r16) * 32 + k8);
        #pragma unroll
        for (int mt = 0; mt < FM; mt++)
            #pragma unroll
            for (int nt = 0; nt < 4; nt++) {
                acc[mt][nt] = mfma(afh[mt], wf[nt], acc[mt][nt]);
                acc[mt][nt] = mfma(afl[mt], wf[nt], acc[mt][nt]);
            }
        __syncthreads();
    }
    #pragma unroll
    for (int nt = 0; nt < 4; nt++) {
        const int n = n0 + wn * 64 + nt * 16 + r16;
        float bv = 0.f;
        if constexpr (BIAS) bv = bias[(int64_t)z * sBias + n];
        #pragma unroll
        for (int mt = 0; mt < FM; mt++) {
            const int mb = m0 + wm * (BM / 2) + mt * 16 + (lane >> 4) * 4;
            #pragma unroll
            for (int r = 0; r < 4; r++) {
                float v = acc[mt][nt][r] + bv;
                if constexpr (TANH) v = tanhf(v);
                const int64_t co = (int64_t)z * sC + (int64_t)(mb + r) * ldc + n;
                if constexpr (OM == 0) {
                    C[co] = v;
                } else {
                    bf16 hh = f2b(v);
                    Chi[co] = hh;
                    Clo[co] = f2b(v - b2f(hh));
                }
            }
        }
    }
}

__global__ void presplit_k(const float* __restrict__ x, bf16* __restrict__ hi,
                           bf16* __restrict__ lo, int n)
{
    const int i = blockIdx.x * 256 + threadIdx.x;
    if (i < n) {
        float v = x[i];
        bf16 h = f2b(v);
        hi[i] = h;
        lo[i] = f2b(v - b2f(h));
    }
}

// fp32 -> single rounded bf16 (matches gemmWf's in-kernel rounding)
__global__ void presplitH_k(const float* __restrict__ x, bf16* __restrict__ hi, int n)
{
    const int i = blockIdx.x * 256 + threadIdx.x;
    if (i < n) hi[i] = f2b(x[i]);
}

// embed writing hi/lo pair
__global__ void embed2_k(const int* __restrict__ toks, const float* __restrict__ tab,
                         bf16* __restrict__ ohi, bf16* __restrict__ olo, int shifted)
{
    const int row = blockIdx.x;
    int tok;
    if (shifted) {
        const int t = row / NB, b = row - t * NB;
        tok = (t == 0) ? SOST : toks[(t - 1) * NB + b];
    } else {
        tok = toks[row];
    }
    const float4 v = ((const float4*)(tab + (int64_t)tok * HD))[threadIdx.x];
    bf16 h0 = f2b(v.x), h1 = f2b(v.y), h2 = f2b(v.z), h3 = f2b(v.w);
    bf16 hv[4] = {h0, h1, h2, h3};
    bf16 lv[4] = {f2b(v.x - b2f(h0)), f2b(v.y - b2f(h1)),
                  f2b(v.z - b2f(h2)), f2b(v.w - b2f(h3))};
    *(uint2*)(ohi + (int64_t)row * HD + threadIdx.x * 4) = *(uint2*)hv;
    *(uint2*)(olo + (int64_t)row * HD + threadIdx.x * 4) = *(uint2*)lv;
}

// =====================================================================
// Persistent encoder layer (all-to-all barrier).
// Grid (HHD/16=32, 2 dirs) x 256 thr.
// =====================================================================
__global__ __launch_bounds__(256, 1) void enc_persist_k(
    const float* __restrict__ gi,
    const bf16* __restrict__ whhHi,
    const bf16* __restrict__ whhLo,
    const float* __restrict__ bhh,
    float* __restrict__ h32,
    bf16* __restrict__ hsHi, bf16* __restrict__ hsLo,
    bf16* __restrict__ yHi, bf16* __restrict__ yLo,
    float* __restrict__ dh32, bf16* __restrict__ dhHi, bf16* __restrict__ dhLo,
    int* __restrict__ flags)
{
    __shared__ f32x4 red[4][6][64];
    const int d = blockIdx.y;
    const int j0 = blockIdx.x * 16;
    const int tid = threadIdx.x;
    const int lane = tid & 63, wid = tid >> 6;
    const int r16 = lane & 15, k8 = (lane >> 4) * 8;
    const int kq = wid * 128;
    const bf16* WdH = whhHi + (int64_t)d * 3 * HHD * HHD;
    const bf16* WdL = whhLo + (int64_t)d * 3 * HHD * HHD;
    const int j = j0 + r16;
    const int myid = d * 32 + blockIdx.x;

    bf16x8 wh[3][4], wl[3][4];
    #pragma unroll
    for (int g = 0; g < 3; g++)
        #pragma unroll
        for (int kk = 0; kk < 4; kk++) {
            const int64_t wo = (int64_t)(g * HHD + j0 + r16) * HHD + kq + kk * 32 + k8;
            wh[g][kk] = ld8(WdH + wo);
            wl[g][kk] = ld8(WdL + wo);
        }
    const float br = bhh[d * 3 * HHD + j];
    const float bz = bhh[d * 3 * HHD + HHD + j];
    const float bn = bhh[d * 3 * HHD + 2 * HHD + j];

    for (int s = 0; s < LI; s++) {
        const int t = d ? (LI - 1 - s) : s;
        const int par = s & 1, npar = par ^ 1;
        const bf16* rH = hsHi + (size_t)s * ESLOT + (size_t)d * NB * HHD;
        const bf16* rL = hsLo + (size_t)s * ESLOT + (size_t)d * NB * HHD;

        f32x4 acc[2][3];
        #pragma unroll
        for (int m = 0; m < 2; m++)
            #pragma unroll
            for (int g = 0; g < 3; g++) acc[m][g] = f32x4{0.f, 0.f, 0.f, 0.f};

        #pragma unroll
        for (int kk = 0; kk < 4; kk++) {
            const int o0 = r16 * HHD + kq + kk * 32 + k8;
            const int o1 = (16 + r16) * HHD + kq + kk * 32 + k8;
            bf16x8 a0h = ld8(rH + o0), a0l = ld8(rL + o0);
            bf16x8 a1h = ld8(rH + o1), a1l = ld8(rL + o1);
            #pragma unroll
            for (int g = 0; g < 3; g++) {
                acc[0][g] = mfma3(a0h, a0l, wh[g][kk], wl[g][kk], acc[0][g]);
                acc[1][g] = mfma3(a1h, a1l, wh[g][kk], wl[g][kk], acc[1][g]);
            }
        }
        #pragma unroll
        for (int m = 0; m < 2; m++)
            #pragma unroll
            for (int g = 0; g < 3; g++)
                red[wid][m * 3 + g][lane] = acc[m][g];
        __syncthreads();
        if (wid == 0) {
            f32x4 a2[2][3];
            #pragma unroll
            for (int m = 0; m < 2; m++)
                #pragma unroll
                for (int g = 0; g < 3; g++)
                    a2[m][g] = red[0][m * 3 + g][lane] + red[1][m * 3 + g][lane]
                             + red[2][m * 3 + g][lane] + red[3][m * 3 + g][lane];
            const float* gid = gi + ((int64_t)d * LI * NB + (int64_t)t * NB) * (3 * HHD);
            bf16* wH = hsHi + (size_t)(s + 1) * ESLOT + (size_t)d * NB * HHD;
            bf16* wL = hsLo + (size_t)(s + 1) * ESLOT + (size_t)d * NB * HHD;
            const int64_t hbase = (int64_t)(par * 2 + d) * NB * HHD;
            #pragma unroll
            for (int mt = 0; mt < 2; mt++)
                #pragma unroll
                for (int r = 0; r < 4; r++) {
                    const int b = mt * 16 + (lane >> 4) * 4 + r;
                    const float ir  = gid[b * 3 * HHD + j];
                    const float iz  = gid[b * 3 * HHD + HHD + j];
                    const float inn = gid[b * 3 * HHD + 2 * HHD + j];
                    const float rg = sigm(ir + a2[mt][0][r] + br);
                    const float zg = sigm(iz + a2[mt][1][r] + bz);
                    const float ng = tanhf(inn + rg * (a2[mt][2][r] + bn));
                    const float hold = h32[hbase + (int64_t)b * HHD + j];
                    const float hnew = (1.f - zg) * ng + zg * hold;
                    bf16 hh = f2b(hnew);
                    bf16 hl = f2b(hnew - b2f(hh));
                    h32[(int64_t)(npar * 2 + d) * NB * HHD + (int64_t)b * HHD + j] = hnew;
                    const int lo_ = b * HHD + j;
                    const float hn2 = __shfl_xor(hnew, 1);
                    if (s < LI - 1 && !(lane & 1)) {
                        bf16 hh2 = f2b(hn2);
                        bf16 hl2 = f2b(hn2 - b2f(hh2));
                        stc2(wH + lo_, hh, hh2);
                        stc2(wL + lo_, hl, hl2);
                    }
                    const int64_t yo = ((int64_t)t * NB + b) * HD + d * HHD + j;
                    yHi[yo] = hh;
                    yLo[yo] = hl;
                    if (s == LI - 1) {
                        const int64_t dof = (int64_t)b * HD + d * HHD + j;
                        dh32[dof] = hnew;
                        dhHi[dof] = hh;
                        dhLo[dof] = hl;
                    }
                }
        }
        if (s < LI - 1) gbarA(flags, 64, myid, s + 1);
    }
}

// =====================================================================
// Decoder PER-STEP kernel (round-14, passing/unchanged).
// =====================================================================
__global__ __launch_bounds__(512) void dec_step_k(
    const float* __restrict__ gi0,
    const bf16* __restrict__ wih1Hi, const bf16* __restrict__ wih1Lo,
    const bf16* __restrict__ whh0Hi, const bf16* __restrict__ whh0Lo,
    const bf16* __restrict__ whh1Hi, const bf16* __restrict__ whh1Lo,
    const float* __restrict__ bih1,
    const float* __restrict__ bhh0,
    const float* __restrict__ bhh1,
    float* __restrict__ h32,
    bf16* __restrict__ hsHi, bf16* __restrict__ hsLo,
    bf16* __restrict__ rnnHi, bf16* __restrict__ rnnLo,
    f32x4* __restrict__ part,
    int* __restrict__ flagd,
    int s)
{
    __shared__ f32x4 red[8][8][64];
    const int tid = threadIdx.x;
    const int lane = tid & 63, wid = tid >> 6;
    const int r16 = lane & 15, k8 = (lane >> 4) * 8;
    const int j0 = blockIdx.x * 16;
    const int j = j0 + r16;

    if (blockIdx.y == 0) {
        if (s >= LO) return;
        const int t = s, par = t & 1, npar = par ^ 1;
        const int kq = wid * 128;
        bf16x8 wh[3][4], wl[3][4];
        #pragma unroll
        for (int g = 0; g < 3; g++)
            #pragma unroll
            for (int kk = 0; kk < 4; kk++) {
                const int64_t wo = (int64_t)(g * HD + j0 + r16) * HD + kq + kk * 32 + k8;
                wh[g][kk] = ld8(whh0Hi + wo);
                wl[g][kk] = ld8(whh0Lo + wo);
            }
        const bf16* rH = hsHi + (size_t)s * DSLOT;
        const bf16* rL = hsLo + (size_t)s * DSLOT;
        f32x4 acc[2][3];
        #pragma unroll
        for (int m = 0; m < 2; m++)
            #pragma unroll
            for (int g = 0; g < 3; g++) acc[m][g] = f32x4{0.f, 0.f, 0.f, 0.f};
        #pragma unroll
        for (int kk = 0; kk < 4; kk++) {
            const int o0 = r16 * HD + kq + kk * 32 + k8;
            const int o1 = (16 + r16) * HD + kq + kk * 32 + k8;
            bf16x8 a0h = ld8(rH + o0), a0l = ld8(rL + o0);
            bf16x8 a1h = ld8(rH + o1), a1l = ld8(rL + o1);
            #pragma unroll
            for (int g = 0; g < 3; g++) {
                acc[0][g] = mfma3(a0h, a0l, wh[g][kk], wl[g][kk], acc[0][g]);
                acc[1][g] = mfma3(a1h, a1l, wh[g][kk], wl[g][kk], acc[1][g]);
            }
        }
        #pragma unroll
        for (int m = 0; m < 2; m++)
            #pragma unroll
            for (int g = 0; g < 3; g++)
                red[wid][m * 3 + g][lane] = acc[m][g];
        __syncthreads();
        if (wid == 0) {
            const float b0r = bhh0[j], b0z = bhh0[HD + j], b0n = bhh0[2 * HD + j];
            f32x4 a2[2][3];
            #pragma unroll
            for (int m = 0; m < 2; m++)
                #pragma unroll
                for (int g = 0; g < 3; g++) {
                    f32x4 v = red[0][m * 3 + g][lane];
                    #pragma unroll
                    for (int w2 = 1; w2 < 8; w2++) v += red[w2][m * 3 + g][lane];
                    a2[m][g] = v;
                }
            const float* gid = gi0 + (int64_t)t * NB * 3 * HD;
            bf16* wHs = hsHi + (size_t)(s + 1) * DSLOT;
            bf16* wLs = hsLo + (size_t)(s + 1) * DSLOT;
            const int64_t hb = (int64_t)(par * NLAY + 0) * NB * HD;
            #pragma unroll
            for (int mt = 0; mt < 2; mt++)
                #pragma unroll
                for (int r = 0; r < 4; r++) {
                    const int b = mt * 16 + (lane >> 4) * 4 + r;
                    const float ir  = gid[b * 3 * HD + j];
                    const float iz  = gid[b * 3 * HD + HD + j];
                    const float inn = gid[b * 3 * HD + 2 * HD + j];
                    const float rg = sigm(ir + a2[mt][0][r] + b0r);
                    const float zg = sigm(iz + a2[mt][1][r] + b0z);
                    const float ng = tanhf(inn + rg * (a2[mt][2][r] + b0n));
                    const float hold = h32[hb + (int64_t)b * HD + j];
                    const float hnew = (1.f - zg) * ng + zg * hold;
                    bf16 hh = f2b(hnew);
                    bf16 hl = f2b(hnew - b2f(hh));
                    h32[(int64_t)(npar * NLAY + 0) * NB * HD + (int64_t)b * HD + j] = hnew;
                    const int lo_ = b * HD + j;
                    wHs[lo_] = hh;
                    wLs[lo_] = hl;
                }
        }
    } else {
        if (s < 1) return;
        const int t = s - 1;
        const int p1 = t & 1, np1 = p1 ^ 1;
        const int kh = blockIdx.y - 1;
        const int kb = kh * 512 + wid * 64;
        bf16x8 wIh[3][2], wIl[3][2], wHh[3][2], wHl[3][2];
        #pragma unroll
        for (int g = 0; g < 3; g++)
            #pragma unroll
            for (int kk = 0; kk < 2; kk++) {
                const int64_t wo = (int64_t)(g * HD + j0 + r16) * HD + kb + kk * 32 + k8;
                wIh[g][kk] = ld8(wih1Hi + wo);
                wIl[g][kk] = ld8(wih1Lo + wo);
                wHh[g][kk] = ld8(whh1Hi + wo);
                wHl[g][kk] = ld8(whh1Lo + wo);
            }
        const bf16* xH = hsHi + (size_t)s * DSLOT;
        const bf16* xL = hsLo + (size_t)s * DSLOT;
        const bf16* yH = hsHi + (size_t)(s - 1) * DSLOT + (size_t)NB * HD;
        const bf16* yL = hsLo + (size_t)(s - 1) * DSLOT + (size_t)NB * HD;
        f32x4 arz[2][2], ain[2], ahn[2];
        #pragma unroll
        for (int i = 0; i < 2; i++) {
            arz[i][0] = f32x4{0.f, 0.f, 0.f, 0.f};
            arz[i][1] = f32x4{0.f, 0.f, 0.f, 0.f};
            ain[i] = f32x4{0.f, 0.f, 0.f, 0.f};
            ahn[i] = f32x4{0.f, 0.f, 0.f, 0.f};
        }
        #pragma unroll
        for (int kk = 0; kk < 2; kk++) {
            const int o0 = r16 * HD + kb + kk * 32 + k8;
            const int o1 = (16 + r16) * HD + kb + kk * 32 + k8;
            bf16x8 x0h = ld8(xH + o0), x0l = ld8(xL + o0);
            bf16x8 x1h = ld8(xH + o1), x1l = ld8(xL + o1);
            bf16x8 y0h = ld8(yH + o0), y0l = ld8(yL + o0);
            bf16x8 y1h = ld8(yH + o1), y1l = ld8(yL + o1);
            arz[0][0] = mfma3(x0h, x0l, wIh[0][kk], wIl[0][kk], arz[0][0]);
            arz[0][0] = mfma3(y0h, y0l, wHh[0][kk], wHl[0][kk], arz[0][0]);
            arz[1][0] = mfma3(x1h, x1l, wIh[0][kk], wIl[0][kk], arz[1][0]);
            arz[1][0] = mfma3(y1h, y1l, wHh[0][kk], wHl[0][kk], arz[1][0]);
            arz[0][1] = mfma3(x0h, x0l, wIh[1][kk], wIl[1][kk], arz[0][1]);
            arz[0][1] = mfma3(y0h, y0l, wHh[1][kk], wHl[1][kk], arz[0][1]);
            arz[1][1] = mfma3(x1h, x1l, wIh[1][kk], wIl[1][kk], arz[1][1]);
            arz[1][1] = mfma3(y1h, y1l, wHh[1][kk], wHl[1][kk], arz[1][1]);
            ain[0] = mfma3(x0h, x0l, wIh[2][kk], wIl[2][kk], ain[0]);
            ain[1] = mfma3(x1h, x1l, wIh[2][kk], wIl[2][kk], ain[1]);
            ahn[0] = mfma3(y0h, y0l, wHh[2][kk], wHl[2][kk], ahn[0]);
            ahn[1] = mfma3(y1h, y1l, wHh[2][kk], wHl[2][kk], ahn[1]);
        }
        red[wid][0][lane] = arz[0][0];
        red[wid][1][lane] = arz[1][0];
        red[wid][2][lane] = arz[0][1];
        red[wid][3][lane] = arz[1][1];
        red[wid][4][lane] = ain[0];
        red[wid][5][lane] = ain[1];
        red[wid][6][lane] = ahn[0];
        red[wid][7][lane] = ahn[1];
        __syncthreads();
        if (wid == 0) {
            f32x4 p[8];
            #pragma unroll
            for (int grp = 0; grp < 8; grp++) {
                f32x4 v = red[0][grp][lane];
                #pragma unroll
                for (int w2 = 1; w2 < 8; w2++) v += red[w2][grp][lane];
                p[grp] = v;
            }
            if (kh == 1) {
                #pragma unroll
                for (int grp = 0; grp < 8; grp++)
                    stc4f((float*)&part[((size_t)blockIdx.x * 8 + grp) * 64 + lane], p[grp]);
                asm volatile("s_waitcnt vmcnt(0)" ::: "memory");
                if (lane == 0)
                    __hip_atomic_store(&flagd[blockIdx.x * BSTR], s, __ATOMIC_RELAXED, __HIP_MEMORY_SCOPE_AGENT);
            } else {
                while (__hip_atomic_load(&flagd[blockIdx.x * BSTR], __ATOMIC_RELAXED, __HIP_MEMORY_SCOPE_AGENT) < s)
                    __builtin_amdgcn_s_sleep(1);
                asm volatile("" ::: "memory");
                #pragma unroll
                for (int grp = 0; grp < 8; grp++)
                    p[grp] += ldc4f((const float*)&part[((size_t)blockIdx.x * 8 + grp) * 64 + lane]);
                const float brr = bih1[j] + bhh1[j];
                const float bzz = bih1[HD + j] + bhh1[HD + j];
                const float bin = bih1[2 * HD + j];
                const float bhn = bhh1[2 * HD + j];
                bf16* wHs = hsHi + (size_t)s * DSLOT + (size_t)NB * HD;
                bf16* wLs = hsLo + (size_t)s * DSLOT + (size_t)NB * HD;
                const int64_t h1b = (int64_t)(p1 * NLAY + 1) * NB * HD;
                #pragma unroll
                for (int mt = 0; mt < 2; mt++)
                    #pragma unroll
                    for (int r = 0; r < 4; r++) {
                        const int b = mt * 16 + (lane >> 4) * 4 + r;
                        const float rg = sigm(p[0 + mt][r] + brr);
                        const float zg = sigm(p[2 + mt][r] + bzz);
                        const float ng = tanhf(p[4 + mt][r] + bin + rg * (p[6 + mt][r] + bhn));
                        const float hold = h32[h1b + (int64_t)b * HD + j];
                        const float hnew = (1.f - zg) * ng + zg * hold;
                        bf16 hh = f2b(hnew);
                        bf16 hl = f2b(hnew - b2f(hh));
                        h32[(int64_t)(np1 * NLAY + 1) * NB * HD + (int64_t)b * HD + j] = hnew;
                        const int lo_ = b * HD + j;
                        wHs[lo_] = hh;
                        wLs[lo_] = hl;
                        const int64_t ro = ((int64_t)t * NB + b) * HD + j;
                        rnnHi[ro] = hh;
                        rnnLo[ro] = hl;
                    }
            }
        }
    }
}

// =====================================================================
__global__ __launch_bounds__(64) void softmax_k(const float* __restrict__ sc,
                                                float* __restrict__ aout)
{
    const int row = blockIdx.x, l = threadIdx.x;
    float v0 = sc[row * LI + l], v1 = sc[row * LI + 64 + l];
    float m = fmaxf(v0, v1);
    #pragma unroll
    for (int o = 32; o > 0; o >>= 1) m = fmaxf(m, __shfl_xor(m, o));
    float e0 = expf(v0 - m), e1 = expf(v1 - m);
    float s = e0 + e1;
    #pragma unroll
    for (int o = 32; o > 0; o >>= 1) s += __shfl_xor(s, o);
    const float inv = 1.f / s;
    aout[row * LI + l] = e0 * inv;
    aout[row * LI + 64 + l] = e1 * inv;
}

// ctx from hi/lo enc outputs -> hi/lo JIN
__global__ __launch_bounds__(256) void ctx2_k(const float* __restrict__ at,
                                              const bf16* __restrict__ eHi,
                                              const bf16* __restrict__ eLo,
                                              bf16* __restrict__ jHi,
                                              bf16* __restrict__ jLo)
{
    const int b = blockIdx.y, h0 = blockIdx.x * 128;
    __shared__ __align__(16) float al[LO][LI];
    for (int i = threadIdx.x; i < LO * LI; i += 256) {
        const int to = i >> 7, ti = i & 127;
        al[to][ti] = at[(to * NB + b) * LI + ti];
    }
    __syncthreads();
    const int hc = h0 + (threadIdx.x & 127);
    const int rh = threadIdx.x >> 7;
    float acc[32];
    #pragma unroll
    for (int i = 0; i < 32; i++) acc[i] = 0.f;
    for (int t = 0; t < LI; t++) {
        const int64_t eo = ((int64_t)t * NB + b) * HD + hc;
        const float ev = b2f(eHi[eo]) + b2f(eLo[eo]);
        #pragma unroll
        for (int i = 0; i < 32; i++) acc[i] += ev * al[rh * 32 + i][t];
    }
    #pragma unroll
    for (int i = 0; i < 32; i++) {
        const int64_t jo = ((int64_t)(rh * 32 + i) * NB + b) * (2 * HD) + hc;
        bf16 hh = f2b(acc[i]);
        jHi[jo] = hh;
        jLo[jo] = f2b(acc[i] - b2f(hh));
    }
}

// copy RNN hi/lo into JIN[:, HD:2HD]
__global__ void rnncopy2_k(const bf16* __restrict__ rHi, const bf16* __restrict__ rLo,
                           bf16* __restrict__ jHi, bf16* __restrict__ jLo)
{
    const int idx = blockIdx.x * 256 + threadIdx.x;
    const int row = idx >> 8;
    const int c = idx & 255;
    ((uint2*)jHi)[(int64_t)row * 512 + 256 + c] = ((const uint2*)rHi)[idx];
    ((uint2*)jLo)[(int64_t)row * 512 + 256 + c] = ((const uint2*)rLo)[idx];
}

// =====================================================================
extern "C" void kernel_launch(void* const* d_in, const int* in_sizes, int n_in,
                              void* d_out, int out_size, void* d_ws, size_t ws_size,
                              hipStream_t stream)
{
    (void)in_sizes; (void)n_in; (void)out_size;
    const int*   in_tok   = (const int*)d_in[0];
    const int*   out_tok  = (const int*)d_in[2];
    const float* enc_emb  = (const float*)d_in[4];
    const float* enc_wih  = (const float*)d_in[5];
    const float* enc_whh  = (const float*)d_in[6];
    const float* enc_bih  = (const float*)d_in[7];
    const float* enc_bhh  = (const float*)d_in[8];
    const float* dec_emb  = (const float*)d_in[9];
    const float* dec_wih  = (const float*)d_in[10];
    const float* dec_whh  = (const float*)d_in[11];
    const float* dec_bih  = (const float*)d_in[12];
    const float* dec_bhh  = (const float*)d_in[13];
    const float* attn_W   = (const float*)d_in[14];
    const float* joiner_W = (const float*)d_in[15];
    const float* joiner_b = (const float*)d_in[16];
    const float* proj_W   = (const float*)d_in[17];
    const float* proj_b   = (const float*)d_in[18];
    float* logits   = (float*)d_out;
    float* attn_out = logits + (size_t)LO * NB * NV;

    const size_t MB = 1ull << 20;
    char* o = (char*)d_out;   // logits region = 250 MiB fp32
    bf16* XB0HI  = (bf16*)(o);               // 8 MiB (dead after L0 gi)
    bf16* XB0LO  = (bf16*)(o + 8 * MB);      // 8 MiB
    bf16* XB1HI  = (bf16*)(o + 16 * MB);     // 8 MiB
    bf16* XB1LO  = (bf16*)(o + 24 * MB);     // 8 MiB
    bf16* EOUTHI = (bf16*)(o + 32 * MB);     // 8 MiB (alive until ctx)
    bf16* EOUTLO = (bf16*)(o + 40 * MB);     // 8 MiB
    float* PENC  = (float*)(o + 48 * MB);    // 16 MiB fp32
    float* GI    = (float*)(o + 64 * MB);    // 48 MiB fp32
    float* DGI0  = (float*)(o + 112 * MB);   // 24 MiB fp32
    bf16* ENCH_HI = (bf16*)(o + 136 * MB);   // 8 MiB per-step slots
    bf16* ENCH_LO = (bf16*)(o + 144 * MB);   // 8 MiB
    bf16* JINHI  = (bf16*)(o + 152 * MB);    // 8 MiB (written post-dec)
    bf16* JINLO  = (bf16*)(o + 160 * MB);    // 8 MiB
    bf16* RNNHI  = (bf16*)(o + 168 * MB);    // 4 MiB
    bf16* RNNLO  = (bf16*)(o + 172 * MB);    // 4 MiB
    float* SC    = (float*)(o + 176 * MB);   // 1 MiB
    bf16* WencHi = (bf16*)(o + 177 * MB);    // 6 MiB
    bf16* WencLo = (bf16*)(o + 183 * MB);    // 6 MiB
    bf16* WdhHi  = (bf16*)(o + 189 * MB);    // 12 MiB
    bf16* WdhLo  = (bf16*)(o + 201 * MB);    // 12 MiB
    bf16* Wih1Hi = (bf16*)(o + 213 * MB);    // 6 MiB
    bf16* Wih1Lo = (bf16*)(o + 219 * MB);    // 6 MiB
    char* ba     = o + 225 * MB;             // 1 MiB: FL_E + FLAGD
    f32x4* PART  = (f32x4*)(o + 228 * MB);   // 0.5 MiB
    bf16* DEMBHI = (bf16*)(o + 229 * MB);    // 4 MiB
    bf16* DEMBLO = (bf16*)(o + 233 * MB);    // 4 MiB
    bf16* WATTB  = (bf16*)(o + 237 * MB);    // 2 MiB attn_W bf16
    bf16* WJOINB = (bf16*)(o + 239 * MB);    // 4 MiB joiner_W bf16
    bf16* WDIH0B = (bf16*)(o + 243 * MB);    // 6 MiB dec_wih[0] bf16 -> 249
    bf16* DECH_HI = XB0HI;                   // dec per-step slots (XB0 dead)
    bf16* DECH_LO = JINHI;                   // (JIN written post-dec)

    char* w = (char*)d_ws;
    bf16* VECSHI = (bf16*)(w);                        // 4 MiB
    bf16* VECSLO = (bf16*)(w + 4 * MB);               // 4 MiB
    float* EH32  = (float*)(w + 8 * MB);              // 512 KiB
    float* DH32  = (float*)(w + 8 * MB + 524288);     // 512 KiB
    // bf16 proj_W only if workspace is big enough (no overlap with output!)
    const bool bigws = (ws_size >= (size_t)80 * MB);
    bf16* PROJW = (bf16*)(w + 12 * MB);               // 62.5 MiB if bigws

    int* FL_E  = (int*)(ba);                 // 64 x 8KB = 512 KiB
    int* FLAGD = (int*)(ba + 512 * 1024);    // 64 x 8KB = 512 KiB

    hipMemsetAsync(ba, 0, 1 * MB, stream);
    hipMemsetAsync(ENCH_HI, 0, (size_t)ESLOT * 2, stream);   // enc slot 0 = zeros
    hipMemsetAsync(ENCH_LO, 0, (size_t)ESLOT * 2, stream);

    // ---- pre-split recurrent weights (hi/lo) + GEMM weights (bf16) ----
    const int nEnc = NLAY * 2 * 3 * HHD * HHD;
    const int nDhh = NLAY * 3 * HD * HD;
    const int nIh1 = 3 * HD * HD;
    presplit_k<<<dim3((nEnc + 255) / 256), dim3(256), 0, stream>>>(enc_whh, WencHi, WencLo, nEnc);
    presplit_k<<<dim3((nDhh + 255) / 256), dim3(256), 0, stream>>>(dec_whh, WdhHi, WdhLo, nDhh);
    presplit_k<<<dim3((nIh1 + 255) / 256), dim3(256), 0, stream>>>(dec_wih + (size_t)3 * HD * HD, Wih1Hi, Wih1Lo, nIh1);
    presplitH_k<<<dim3((HD * HD + 255) / 256), dim3(256), 0, stream>>>(attn_W, WATTB, HD * HD);
    presplitH_k<<<dim3((HD * 2 * HD + 255) / 256), dim3(256), 0, stream>>>(joiner_W, WJOINB, HD * 2 * HD);
    presplitH_k<<<dim3((3 * HD * HD + 255) / 256), dim3(256), 0, stream>>>(dec_wih, WDIH0B, 3 * HD * HD);
    if (bigws)
        presplitH_k<<<dim3((NV * HD + 255) / 256), dim3(256), 0, stream>>>(proj_W, PROJW, NV * HD);

    // ---- decoder prep (bf16-W GEMM) ----
    embed2_k<<<dim3(LO * NB), dim3(256), 0, stream>>>(out_tok, dec_emb, DEMBHI, DEMBLO, 1);
    gemmBW_k<128, true, false, 0><<<dim3(3 * HD / 128, LO * NB / 128, 1), 256, 0, stream>>>(
        DEMBHI, DEMBLO, HD, 0, WDIH0B, HD, 0,
        DGI0, nullptr, nullptr, 3 * HD, 0, dec_bih, 0, HD);

    // ---- encoder (persistent, all-to-all barrier) ----
    embed2_k<<<dim3(LI * NB), dim3(256), 0, stream>>>(in_tok, enc_emb, XB0HI, XB0LO, 0);
    for (int l = 0; l < NLAY; l++) {
        const bf16* XinH = l ? XB1HI : XB0HI;
        const bf16* XinL = l ? XB1LO : XB0LO;
        bf16* YoH = l ? EOUTHI : XB1HI;
        bf16* YoL = l ? EOUTLO : XB1LO;
        hipMemsetAsync(EH32, 0, (size_t)2 * 2 * NB * HHD * 4, stream);
        gemmWf_k<128, true, false, 0><<<dim3(3 * HHD / 128, LI * NB / 128, 2), 256, 0, stream>>>(
            XinH, XinL, HD, 0,
            enc_wih + (size_t)l * 2 * 3 * HHD * HD, HD, (int64_t)3 * HHD * HD,
            GI, nullptr, nullptr, 3 * HHD, (int64_t)LI * NB * 3 * HHD,
            enc_bih + l * 2 * 3 * HHD, 3 * HHD, HD);
        enc_persist_k<<<dim3(HHD / 16, 2), dim3(256), 0, stream>>>(
            GI,
            WencHi + (size_t)l * 2 * 3 * HHD * HHD,
            WencLo + (size_t)l * 2 * 3 * HHD * HHD,
            enc_bhh + l * 2 * 3 * HHD,
            EH32, ENCH_HI, ENCH_LO, YoH, YoL,
            DH32 + (size_t)l * NB * HD,
            DECH_HI + (size_t)l * NB * HD,
            DECH_LO + (size_t)l * NB * HD,
            FL_E);
        if (l == 0) hipMemsetAsync(FL_E, 0, 512 * 1024, stream);
    }

    // proj_enc = enc_outputs @ attn_W^T (bf16 W)
    gemmBW_k<128, false, false, 0><<<dim3(HD / 128, LI * NB / 128, 1), 256, 0, stream>>>(
        EOUTHI, EOUTLO, HD, 0, WATTB, HD, 0,
        PENC, nullptr, nullptr, HD, 0, nullptr, 0, HD);

    // ---- decoder recurrence: 65 per-step launches ----
    for (int s = 0; s <= LO; s++)
        dec_step_k<<<dim3(HD / 16, 3), dim3(512), 0, stream>>>(
            DGI0,
            Wih1Hi, Wih1Lo,
            WdhHi, WdhLo,
            WdhHi + (size_t)3 * HD * HD, WdhLo + (size_t)3 * HD * HD,
            dec_bih + 3 * HD, dec_bhh, dec_bhh + 3 * HD,
            DH32, DECH_HI, DECH_LO, RNNHI, RNNLO, PART, FLAGD, s);

    // ---- batched epilogue ----
    gemmWf_k<64, false, false, 0><<<dim3(1, 1, NB), 256, 0, stream>>>(
        RNNHI, RNNLO, (int64_t)NB * HD, HD, PENC, (int64_t)NB * HD, HD,
        SC, nullptr, nullptr, (int64_t)NB * LI, LI, nullptr, 0, HD);
    softmax_k<<<dim3(LO * NB), dim3(64), 0, stream>>>(SC, attn_out);
    ctx2_k<<<dim3(HD / 128, NB), dim3(256), 0, stream>>>(attn_out, EOUTHI, EOUTLO, JINHI, JINLO);
    rnncopy2_k<<<dim3(LO * NB * HD / 4 / 256), dim3(256), 0, stream>>>(RNNHI, RNNLO, JINHI, JINLO);
    gemmBW_k<128, true, true, 1><<<dim3(HD / 128, LO * NB / 128, 1), 256, 0, stream>>>(
        JINHI, JINLO, 2 * HD, 0, WJOINB, 2 * HD, 0,
        nullptr, VECSHI, VECSLO, HD, 0, joiner_b, 0, 2 * HD);
    // logits GEMM: bf16 W from d_ws if it fits, else fp32 proj_W directly.
    if (bigws) {
        gemmBW_k<128, true, false, 0><<<dim3(NV / 128, LO * NB / 128, 1), 256, 0, stream>>>(
            VECSHI, VECSLO, HD, 0, PROJW, HD, 0,
            logits, nullptr, nullptr, NV, 0, proj_b, 0, HD);
    } else {
        gemmWf_k<128, true, false, 0><<<dim3(NV / 128, LO * NB / 128, 1), 256, 0, stream>>>(
            VECSHI, VECSLO, HD, 0, proj_W, HD, 0,
            logits, nullptr, nullptr, NV, 0, proj_b, 0, HD);
    }
}

// Round 18
// 4103.931 us; speedup vs baseline: 1.3153x; 1.0157x over previous
//
#include <hip/hip_runtime.h>
#include <hip/hip_bf16.h>
#include <stdint.h>

// ---- problem constants ----
constexpr int LI   = 128;    // L_IN
constexpr int LO   = 64;     // L_OUT
constexpr int NB   = 32;     // batch
constexpr int HD   = 1024;   // H
constexpr int HHD  = 512;    // HH
constexpr int NLAY = 2;
constexpr int NV   = 32000;  // V_OUT
constexpr int SOST = 1;

// Round-18 (on passing round-17): (1) enc epilogue reorder — only slot
// stores precede the flag; Y/h32/dh writes deferred past the barrier
// (off the producer->L3->consumer critical chain); (2) hot-spin poll;
// (3) M-major grid swap (SW) on big GEMMs so co-scheduled blocks share
// W-tiles in L2 (logits GEMM re-read ~2GB of W via L3 with n-major).

typedef __hip_bfloat16 bf16;
typedef __attribute__((ext_vector_type(8))) short bf16x8;
typedef __attribute__((ext_vector_type(4))) float f32x4;
typedef unsigned long long u64;

constexpr int BSTR = 2048;   // flag stride in ints = 8 KB
constexpr int ESLOT = 2 * NB * HHD;     // enc per-step slot (elems)
constexpr int DSLOT = NLAY * NB * HD;   // dec per-step slot (elems)

__device__ __forceinline__ float b2f(bf16 x) { return __bfloat162float(x); }
__device__ __forceinline__ bf16  f2b(float x) { return __float2bfloat16(x); }
__device__ __forceinline__ float sigm(float x) { return 1.0f / (1.0f + expf(-x)); }

__device__ __forceinline__ f32x4 mfma(bf16x8 a, bf16x8 b, f32x4 c) {
    return __builtin_amdgcn_mfma_f32_16x16x32_bf16(a, b, c, 0, 0, 0);
}
__device__ __forceinline__ f32x4 mfma3(bf16x8 ah, bf16x8 al, bf16x8 bh, bf16x8 bl, f32x4 c) {
    c = mfma(ah, bh, c);
    c = mfma(ah, bl, c);
    c = mfma(al, bh, c);
    return c;
}
__device__ __forceinline__ bf16x8 ld8(const bf16* p) { return *(const bf16x8*)p; }

// async global->LDS, 16B per lane; LDS base wave-uniform
__device__ __forceinline__ void g2l16(const void* g, void* l) {
    __builtin_amdgcn_global_load_lds(
        (const __attribute__((address_space(1))) unsigned int*)g,
        (__attribute__((address_space(3))) unsigned int*)l,
        16, 0, 0);
}

// ---- coherent (agent/L3) helpers ----
__device__ __forceinline__ void stc2(bf16* p, bf16 a, bf16 b) {
    unsigned v = (unsigned)*(const unsigned short*)&a |
                 ((unsigned)*(const unsigned short*)&b << 16);
    __hip_atomic_store((unsigned*)p, v, __ATOMIC_RELAXED, __HIP_MEMORY_SCOPE_AGENT);
}
__device__ __forceinline__ f32x4 ldc4f(const float* p) {
    union { f32x4 v; u64 q[2]; } u;
    u.q[0] = __hip_atomic_load((const u64*)p,     __ATOMIC_RELAXED, __HIP_MEMORY_SCOPE_AGENT);
    u.q[1] = __hip_atomic_load((const u64*)p + 1, __ATOMIC_RELAXED, __HIP_MEMORY_SCOPE_AGENT);
    return u.v;
}
__device__ __forceinline__ void stc4f(float* p, f32x4 v) {
    union { f32x4 v; u64 q[2]; } u;
    u.v = v;
    __hip_atomic_store((u64*)p,     u.q[0], __ATOMIC_RELAXED, __HIP_MEMORY_SCOPE_AGENT);
    __hip_atomic_store((u64*)p + 1, u.q[1], __ATOMIC_RELAXED, __HIP_MEMORY_SCOPE_AGENT);
}

// ---- all-to-all flag barrier (hot spin) ----
__device__ __forceinline__ void gbarA(int* __restrict__ flags,
                                      int nblk, int myid, int val) {
    __syncthreads();
    const int tid = threadIdx.x;
    if (tid < 64) {
        if (tid == 0) {
            asm volatile("s_waitcnt vmcnt(0)" ::: "memory");
            __hip_atomic_store(&flags[myid * BSTR], val, __ATOMIC_RELAXED, __HIP_MEMORY_SCOPE_AGENT);
        }
        bool done = false;
        while (!done) {
            int v = (tid < nblk)
                ? __hip_atomic_load(&flags[tid * BSTR], __ATOMIC_RELAXED, __HIP_MEMORY_SCOPE_AGENT)
                : val;
            done = __all(v >= val);
        }
        asm volatile("" ::: "memory");
    }
    __syncthreads();
}

// =====================================================================
// GEMM (fp32 W, rounded to bf16 in-register). SW: m-major grid.
// =====================================================================
template<int BM, bool BIAS, bool TANH, int OM, int SW>
__global__ __launch_bounds__(256) void gemmWf_k(
    const bf16* __restrict__ Ahi, const bf16* __restrict__ Alo,
    int64_t lda, int64_t sA,
    const float* __restrict__ W, int64_t ldw, int64_t sW,
    float* __restrict__ C, bf16* __restrict__ Chi, bf16* __restrict__ Clo,
    int64_t ldc, int64_t sC,
    const float* __restrict__ bias, int64_t sBias,
    int K)
{
    constexpr int FM = BM / 32;
    __shared__ __align__(16) bf16 Ah[BM * 32], Al[BM * 32];
    __shared__ __align__(16) bf16 Wl[128 * 32];
    const int z    = blockIdx.z;
    const bf16* Abh = Ahi + (int64_t)z * sA;
    const bf16* Abl = Alo + (int64_t)z * sA;
    const float* Wb = W + (int64_t)z * sW;
    const int n0   = (SW ? blockIdx.y : blockIdx.x) * 128;
    const int m0   = (SW ? blockIdx.x : blockIdx.y) * BM;
    const int tid  = threadIdx.x;
    const int lane = tid & 63, wid = tid >> 6;
    const int wm   = wid >> 1, wn = wid & 1;
    const int srow = lane >> 2;
    const int skb  = (lane & 3) * 8;
    const int r16  = lane & 15;
    const int k8   = (lane >> 4) * 8;

    f32x4 acc[FM][4];
    #pragma unroll
    for (int i = 0; i < FM; i++)
        #pragma unroll
        for (int j = 0; j < 4; j++)
            acc[i][j] = f32x4{0.f, 0.f, 0.f, 0.f};

    for (int k0 = 0; k0 < K; k0 += 32) {
        for (int c = wid; c < BM / 16; c += 4) {
            g2l16(Abh + (int64_t)(m0 + c * 16 + srow) * lda + k0 + skb, Ah + c * 512);
            g2l16(Abl + (int64_t)(m0 + c * 16 + srow) * lda + k0 + skb, Al + c * 512);
        }
        for (int c = wid; c < 8; c += 4) {
            const float* wp = Wb + (int64_t)(n0 + c * 16 + srow) * ldw + k0 + skb;
            bf16x8 wv;
            #pragma unroll
            for (int jj = 0; jj < 8; jj++) ((bf16*)&wv)[jj] = f2b(wp[jj]);
            *(bf16x8*)(Wl + c * 512 + lane * 8) = wv;
        }
        __syncthreads();
        bf16x8 afh[FM], afl[FM], wf[4];
        #pragma unroll
        for (int mt = 0; mt < FM; mt++) {
            const int off = (wm * (BM / 2) + mt * 16 + r16) * 32 + k8;
            afh[mt] = ld8(Ah + off);
            afl[mt] = ld8(Al + off);
        }
        #pragma unroll
        for (int nt = 0; nt < 4; nt++)
            wf[nt] = ld8(Wl + (wn * 64 + nt * 16 + r16) * 32 + k8);
        #pragma unroll
        for (int mt = 0; mt < FM; mt++)
            #pragma unroll
            for (int nt = 0; nt < 4; nt++) {
                acc[mt][nt] = mfma(afh[mt], wf[nt], acc[mt][nt]);
                acc[mt][nt] = mfma(afl[mt], wf[nt], acc[mt][nt]);
            }
        __syncthreads();
    }
    #pragma unroll
    for (int nt = 0; nt < 4; nt++) {
        const int n = n0 + wn * 64 + nt * 16 + r16;
        float bv = 0.f;
        if constexpr (BIAS) bv = bias[(int64_t)z * sBias + n];
        #pragma unroll
        for (int mt = 0; mt < FM; mt++) {
            const int mb = m0 + wm * (BM / 2) + mt * 16 + (lane >> 4) * 4;
            #pragma unroll
            for (int r = 0; r < 4; r++) {
                float v = acc[mt][nt][r] + bv;
                if constexpr (TANH) v = tanhf(v);
                const int64_t co = (int64_t)z * sC + (int64_t)(mb + r) * ldc + n;
                if constexpr (OM == 0) {
                    C[co] = v;
                } else {
                    bf16 hh = f2b(v);
                    Chi[co] = hh;
                    Clo[co] = f2b(v - b2f(hh));
                }
            }
        }
    }
}

// =====================================================================
// GEMM with PRE-SPLIT bf16 W. SW: m-major grid. Numerically identical.
// =====================================================================
template<int BM, bool BIAS, bool TANH, int OM, int SW>
__global__ __launch_bounds__(256) void gemmBW_k(
    const bf16* __restrict__ Ahi, const bf16* __restrict__ Alo,
    int64_t lda, int64_t sA,
    const bf16* __restrict__ W, int64_t ldw, int64_t sW,
    float* __restrict__ C, bf16* __restrict__ Chi, bf16* __restrict__ Clo,
    int64_t ldc, int64_t sC,
    const float* __restrict__ bias, int64_t sBias,
    int K)
{
    constexpr int FM = BM / 32;
    __shared__ __align__(16) bf16 Ah[BM * 32], Al[BM * 32];
    __shared__ __align__(16) bf16 Wl[128 * 32];
    const int z    = blockIdx.z;
    const bf16* Abh = Ahi + (int64_t)z * sA;
    const bf16* Abl = Alo + (int64_t)z * sA;
    const bf16* Wb = W + (int64_t)z * sW;
    const int n0   = (SW ? blockIdx.y : blockIdx.x) * 128;
    const int m0   = (SW ? blockIdx.x : blockIdx.y) * BM;
    const int tid  = threadIdx.x;
    const int lane = tid & 63, wid = tid >> 6;
    const int wm   = wid >> 1, wn = wid & 1;
    const int srow = lane >> 2;
    const int skb  = (lane & 3) * 8;
    const int r16  = lane & 15;
    const int k8   = (lane >> 4) * 8;

    f32x4 acc[FM][4];
    #pragma unroll
    for (int i = 0; i < FM; i++)
        #pragma unroll
        for (int j = 0; j < 4; j++)
            acc[i][j] = f32x4{0.f, 0.f, 0.f, 0.f};

    for (int k0 = 0; k0 < K; k0 += 32) {
        for (int c = wid; c < BM / 16; c += 4) {
            g2l16(Abh + (int64_t)(m0 + c * 16 + srow) * lda + k0 + skb, Ah + c * 512);
            g2l16(Abl + (int64_t)(m0 + c * 16 + srow) * lda + k0 + skb, Al + c * 512);
        }
        for (int c = wid; c < 8; c += 4)
            g2l16(Wb + (int64_t)(n0 + c * 16 + srow) * ldw + k0 + skb, Wl + c * 512);
        __syncthreads();
        bf16x8 afh[FM], afl[FM], wf[4];
        #pragma unroll
        for (int mt = 0; mt < FM; mt++) {
            const int off = (wm * (BM / 2) + mt * 16 + r16) * 32 + k8;
            afh[mt] = ld8(Ah + off);
            afl[mt] = ld8(Al + off);
        }
        #pragma unroll
        for (int nt = 0; nt < 4; nt++)
            wf[nt] = ld8(Wl + (wn * 64 + nt * 16 + r16) * 32 + k8);
        #pragma unroll
        for (int mt = 0; mt < FM; mt++)
            #pragma unroll
            for (int nt = 0; nt < 4; nt++) {
                acc[mt][nt] = mfma(afh[mt], wf[nt], acc[mt][nt]);
                acc[mt][nt] = mfma(afl[mt], wf[nt], acc[mt][nt]);
            }
        __syncthreads();
    }
    #pragma unroll
    for (int nt = 0; nt < 4; nt++) {
        const int n = n0 + wn * 64 + nt * 16 + r16;
        float bv = 0.f;
        if constexpr (BIAS) bv = bias[(int64_t)z * sBias + n];
        #pragma unroll
        for (int mt = 0; mt < FM; mt++) {
            const int mb = m0 + wm * (BM / 2) + mt * 16 + (lane >> 4) * 4;
            #pragma unroll
            for (int r = 0; r < 4; r++) {
                float v = acc[mt][nt][r] + bv;
                if constexpr (TANH) v = tanhf(v);
                const int64_t co = (int64_t)z * sC + (int64_t)(mb + r) * ldc + n;
                if constexpr (OM == 0) {
                    C[co] = v;
                } else {
                    bf16 hh = f2b(v);
                    Chi[co] = hh;
                    Clo[co] = f2b(v - b2f(hh));
                }
            }
        }
    }
}

__global__ void presplit_k(const float* __restrict__ x, bf16* __restrict__ hi,
                           bf16* __restrict__ lo, int n)
{
    const int i = blockIdx.x * 256 + threadIdx.x;
    if (i < n) {
        float v = x[i];
        bf16 h = f2b(v);
        hi[i] = h;
        lo[i] = f2b(v - b2f(h));
    }
}

// fp32 -> single rounded bf16
__global__ void presplitH_k(const float* __restrict__ x, bf16* __restrict__ hi, int n)
{
    const int i = blockIdx.x * 256 + threadIdx.x;
    if (i < n) hi[i] = f2b(x[i]);
}

// embed writing hi/lo pair
__global__ void embed2_k(const int* __restrict__ toks, const float* __restrict__ tab,
                         bf16* __restrict__ ohi, bf16* __restrict__ olo, int shifted)
{
    const int row = blockIdx.x;
    int tok;
    if (shifted) {
        const int t = row / NB, b = row - t * NB;
        tok = (t == 0) ? SOST : toks[(t - 1) * NB + b];
    } else {
        tok = toks[row];
    }
    const float4 v = ((const float4*)(tab + (int64_t)tok * HD))[threadIdx.x];
    bf16 h0 = f2b(v.x), h1 = f2b(v.y), h2 = f2b(v.z), h3 = f2b(v.w);
    bf16 hv[4] = {h0, h1, h2, h3};
    bf16 lv[4] = {f2b(v.x - b2f(h0)), f2b(v.y - b2f(h1)),
                  f2b(v.z - b2f(h2)), f2b(v.w - b2f(h3))};
    *(uint2*)(ohi + (int64_t)row * HD + threadIdx.x * 4) = *(uint2*)hv;
    *(uint2*)(olo + (int64_t)row * HD + threadIdx.x * 4) = *(uint2*)lv;
}

// =====================================================================
// Persistent encoder layer. Critical-path-minimized epilogue:
// slot stores -> barrier(flag) -> deferred Y/h32/dh writes.
// Grid (HHD/16=32, 2 dirs) x 256 thr.
// =====================================================================
__global__ __launch_bounds__(256, 1) void enc_persist_k(
    const float* __restrict__ gi,
    const bf16* __restrict__ whhHi,
    const bf16* __restrict__ whhLo,
    const float* __restrict__ bhh,
    float* __restrict__ h32,
    bf16* __restrict__ hsHi, bf16* __restrict__ hsLo,
    bf16* __restrict__ yHi, bf16* __restrict__ yLo,
    float* __restrict__ dh32, bf16* __restrict__ dhHi, bf16* __restrict__ dhLo,
    int* __restrict__ flags)
{
    __shared__ f32x4 red[4][6][64];
    const int d = blockIdx.y;
    const int j0 = blockIdx.x * 16;
    const int tid = threadIdx.x;
    const int lane = tid & 63, wid = tid >> 6;
    const int r16 = lane & 15, k8 = (lane >> 4) * 8;
    const int kq = wid * 128;
    const bf16* WdH = whhHi + (int64_t)d * 3 * HHD * HHD;
    const bf16* WdL = whhLo + (int64_t)d * 3 * HHD * HHD;
    const int j = j0 + r16;
    const int myid = d * 32 + blockIdx.x;

    bf16x8 wh[3][4], wl[3][4];
    #pragma unroll
    for (int g = 0; g < 3; g++)
        #pragma unroll
        for (int kk = 0; kk < 4; kk++) {
            const int64_t wo = (int64_t)(g * HHD + j0 + r16) * HHD + kq + kk * 32 + k8;
            wh[g][kk] = ld8(WdH + wo);
            wl[g][kk] = ld8(WdL + wo);
        }
    const float br = bhh[d * 3 * HHD + j];
    const float bz = bhh[d * 3 * HHD + HHD + j];
    const float bn = bhh[d * 3 * HHD + 2 * HHD + j];

    float hnv0, hnv1, hnv2, hnv3, hnv4, hnv5, hnv6, hnv7;

    for (int s = 0; s < LI; s++) {
        const int t = d ? (LI - 1 - s) : s;
        const int par = s & 1, npar = par ^ 1;
        const bf16* rH = hsHi + (size_t)s * ESLOT + (size_t)d * NB * HHD;
        const bf16* rL = hsLo + (size_t)s * ESLOT + (size_t)d * NB * HHD;

        f32x4 acc[2][3];
        #pragma unroll
        for (int m = 0; m < 2; m++)
            #pragma unroll
            for (int g = 0; g < 3; g++) acc[m][g] = f32x4{0.f, 0.f, 0.f, 0.f};

        #pragma unroll
        for (int kk = 0; kk < 4; kk++) {
            const int o0 = r16 * HHD + kq + kk * 32 + k8;
            const int o1 = (16 + r16) * HHD + kq + kk * 32 + k8;
            bf16x8 a0h = ld8(rH + o0), a0l = ld8(rL + o0);
            bf16x8 a1h = ld8(rH + o1), a1l = ld8(rL + o1);
            #pragma unroll
            for (int g = 0; g < 3; g++) {
                acc[0][g] = mfma3(a0h, a0l, wh[g][kk], wl[g][kk], acc[0][g]);
                acc[1][g] = mfma3(a1h, a1l, wh[g][kk], wl[g][kk], acc[1][g]);
            }
        }
        #pragma unroll
        for (int m = 0; m < 2; m++)
            #pragma unroll
            for (int g = 0; g < 3; g++)
                red[wid][m * 3 + g][lane] = acc[m][g];
        __syncthreads();
        if (wid == 0) {
            f32x4 a2[2][3];
            #pragma unroll
            for (int m = 0; m < 2; m++)
                #pragma unroll
                for (int g = 0; g < 3; g++)
                    a2[m][g] = red[0][m * 3 + g][lane] + red[1][m * 3 + g][lane]
                             + red[2][m * 3 + g][lane] + red[3][m * 3 + g][lane];
            const float* gid = gi + ((int64_t)d * LI * NB + (int64_t)t * NB) * (3 * HHD);
            bf16* wH = hsHi + (size_t)(s + 1) * ESLOT + (size_t)d * NB * HHD;
            bf16* wL = hsLo + (size_t)(s + 1) * ESLOT + (size_t)d * NB * HHD;
            const int64_t hbase = (int64_t)(par * 2 + d) * NB * HHD;
            float hv[2][4];
            // phase 1: compute + ONLY slot stores (critical path)
            #pragma unroll
            for (int mt = 0; mt < 2; mt++)
                #pragma unroll
                for (int r = 0; r < 4; r++) {
                    const int b = mt * 16 + (lane >> 4) * 4 + r;
                    const float ir  = gid[b * 3 * HHD + j];
                    const float iz  = gid[b * 3 * HHD + HHD + j];
                    const float inn = gid[b * 3 * HHD + 2 * HHD + j];
                    const float rg = sigm(ir + a2[mt][0][r] + br);
                    const float zg = sigm(iz + a2[mt][1][r] + bz);
                    const float ng = tanhf(inn + rg * (a2[mt][2][r] + bn));
                    const float hold = h32[hbase + (int64_t)b * HHD + j];
                    const float hnew = (1.f - zg) * ng + zg * hold;
                    hv[mt][r] = hnew;
                    const float hn2 = __shfl_xor(hnew, 1);
                    if (s < LI - 1 && !(lane & 1)) {
                        bf16 hh = f2b(hnew);
                        bf16 hl = f2b(hnew - b2f(hh));
                        bf16 hh2 = f2b(hn2);
                        bf16 hl2 = f2b(hn2 - b2f(hh2));
                        const int lo_ = b * HHD + j;
                        stc2(wH + lo_, hh, hh2);
                        stc2(wL + lo_, hl, hl2);
                    }
                }
            hnv0 = hv[0][0]; hnv1 = hv[0][1]; hnv2 = hv[0][2]; hnv3 = hv[0][3];
            hnv4 = hv[1][0]; hnv5 = hv[1][1]; hnv6 = hv[1][2]; hnv7 = hv[1][3];
        }
        if (s < LI - 1) gbarA(flags, 64, myid, s + 1);
        if (wid == 0) {
            // phase 2 (deferred, overlaps next step / off critical path):
            float hv2[8] = {hnv0, hnv1, hnv2, hnv3, hnv4, hnv5, hnv6, hnv7};
            const int64_t hb2 = (int64_t)(npar * 2 + d) * NB * HHD;
            #pragma unroll
            for (int mt = 0; mt < 2; mt++)
                #pragma unroll
                for (int r = 0; r < 4; r++) {
                    const int b = mt * 16 + (lane >> 4) * 4 + r;
                    const float hnew = hv2[mt * 4 + r];
                    bf16 hh = f2b(hnew);
                    bf16 hl = f2b(hnew - b2f(hh));
                    h32[hb2 + (int64_t)b * HHD + j] = hnew;
                    const int64_t yo = ((int64_t)t * NB + b) * HD + d * HHD + j;
                    yHi[yo] = hh;
                    yLo[yo] = hl;
                    if (s == LI - 1) {
                        const int64_t dof = (int64_t)b * HD + d * HHD + j;
                        dh32[dof] = hnew;
                        dhHi[dof] = hh;
                        dhLo[dof] = hl;
                    }
                }
        }
    }
}

// =====================================================================
// Decoder PER-STEP kernel (round-17, passing/unchanged).
// =====================================================================
__global__ __launch_bounds__(512) void dec_step_k(
    const float* __restrict__ gi0,
    const bf16* __restrict__ wih1Hi, const bf16* __restrict__ wih1Lo,
    const bf16* __restrict__ whh0Hi, const bf16* __restrict__ whh0Lo,
    const bf16* __restrict__ whh1Hi, const bf16* __restrict__ whh1Lo,
    const float* __restrict__ bih1,
    const float* __restrict__ bhh0,
    const float* __restrict__ bhh1,
    float* __restrict__ h32,
    bf16* __restrict__ hsHi, bf16* __restrict__ hsLo,
    bf16* __restrict__ rnnHi, bf16* __restrict__ rnnLo,
    f32x4* __restrict__ part,
    int* __restrict__ flagd,
    int s)
{
    __shared__ f32x4 red[8][8][64];
    const int tid = threadIdx.x;
    const int lane = tid & 63, wid = tid >> 6;
    const int r16 = lane & 15, k8 = (lane >> 4) * 8;
    const int j0 = blockIdx.x * 16;
    const int j = j0 + r16;

    if (blockIdx.y == 0) {
        if (s >= LO) return;
        const int t = s, par = t & 1, npar = par ^ 1;
        const int kq = wid * 128;
        bf16x8 wh[3][4], wl[3][4];
        #pragma unroll
        for (int g = 0; g < 3; g++)
            #pragma unroll
            for (int kk = 0; kk < 4; kk++) {
                const int64_t wo = (int64_t)(g * HD + j0 + r16) * HD + kq + kk * 32 + k8;
                wh[g][kk] = ld8(whh0Hi + wo);
                wl[g][kk] = ld8(whh0Lo + wo);
            }
        const bf16* rH = hsHi + (size_t)s * DSLOT;
        const bf16* rL = hsLo + (size_t)s * DSLOT;
        f32x4 acc[2][3];
        #pragma unroll
        for (int m = 0; m < 2; m++)
            #pragma unroll
            for (int g = 0; g < 3; g++) acc[m][g] = f32x4{0.f, 0.f, 0.f, 0.f};
        #pragma unroll
        for (int kk = 0; kk < 4; kk++) {
            const int o0 = r16 * HD + kq + kk * 32 + k8;
            const int o1 = (16 + r16) * HD + kq + kk * 32 + k8;
            bf16x8 a0h = ld8(rH + o0), a0l = ld8(rL + o0);
            bf16x8 a1h = ld8(rH + o1), a1l = ld8(rL + o1);
            #pragma unroll
            for (int g = 0; g < 3; g++) {
                acc[0][g] = mfma3(a0h, a0l, wh[g][kk], wl[g][kk], acc[0][g]);
                acc[1][g] = mfma3(a1h, a1l, wh[g][kk], wl[g][kk], acc[1][g]);
            }
        }
        #pragma unroll
        for (int m = 0; m < 2; m++)
            #pragma unroll
            for (int g = 0; g < 3; g++)
                red[wid][m * 3 + g][lane] = acc[m][g];
        __syncthreads();
        if (wid == 0) {
            const float b0r = bhh0[j], b0z = bhh0[HD + j], b0n = bhh0[2 * HD + j];
            f32x4 a2[2][3];
            #pragma unroll
            for (int m = 0; m < 2; m++)
                #pragma unroll
                for (int g = 0; g < 3; g++) {
                    f32x4 v = red[0][m * 3 + g][lane];
                    #pragma unroll
                    for (int w2 = 1; w2 < 8; w2++) v += red[w2][m * 3 + g][lane];
                    a2[m][g] = v;
                }
            const float* gid = gi0 + (int64_t)t * NB * 3 * HD;
            bf16* wHs = hsHi + (size_t)(s + 1) * DSLOT;
            bf16* wLs = hsLo + (size_t)(s + 1) * DSLOT;
            const int64_t hb = (int64_t)(par * NLAY + 0) * NB * HD;
            #pragma unroll
            for (int mt = 0; mt < 2; mt++)
                #pragma unroll
                for (int r = 0; r < 4; r++) {
                    const int b = mt * 16 + (lane >> 4) * 4 + r;
                    const float ir  = gid[b * 3 * HD + j];
                    const float iz  = gid[b * 3 * HD + HD + j];
                    const float inn = gid[b * 3 * HD + 2 * HD + j];
                    const float rg = sigm(ir + a2[mt][0][r] + b0r);
                    const float zg = sigm(iz + a2[mt][1][r] + b0z);
                    const float ng = tanhf(inn + rg * (a2[mt][2][r] + b0n));
                    const float hold = h32[hb + (int64_t)b * HD + j];
                    const float hnew = (1.f - zg) * ng + zg * hold;
                    bf16 hh = f2b(hnew);
                    bf16 hl = f2b(hnew - b2f(hh));
                    h32[(int64_t)(npar * NLAY + 0) * NB * HD + (int64_t)b * HD + j] = hnew;
                    const int lo_ = b * HD + j;
                    wHs[lo_] = hh;
                    wLs[lo_] = hl;
                }
        }
    } else {
        if (s < 1) return;
        const int t = s - 1;
        const int p1 = t & 1, np1 = p1 ^ 1;
        const int kh = blockIdx.y - 1;
        const int kb = kh * 512 + wid * 64;
        bf16x8 wIh[3][2], wIl[3][2], wHh[3][2], wHl[3][2];
        #pragma unroll
        for (int g = 0; g < 3; g++)
            #pragma unroll
            for (int kk = 0; kk < 2; kk++) {
                const int64_t wo = (int64_t)(g * HD + j0 + r16) * HD + kb + kk * 32 + k8;
                wIh[g][kk] = ld8(wih1Hi + wo);
                wIl[g][kk] = ld8(wih1Lo + wo);
                wHh[g][kk] = ld8(whh1Hi + wo);
                wHl[g][kk] = ld8(whh1Lo + wo);
            }
        const bf16* xH = hsHi + (size_t)s * DSLOT;
        const bf16* xL = hsLo + (size_t)s * DSLOT;
        const bf16* yH = hsHi + (size_t)(s - 1) * DSLOT + (size_t)NB * HD;
        const bf16* yL = hsLo + (size_t)(s - 1) * DSLOT + (size_t)NB * HD;
        f32x4 arz[2][2], ain[2], ahn[2];
        #pragma unroll
        for (int i = 0; i < 2; i++) {
            arz[i][0] = f32x4{0.f, 0.f, 0.f, 0.f};
            arz[i][1] = f32x4{0.f, 0.f, 0.f, 0.f};
            ain[i] = f32x4{0.f, 0.f, 0.f, 0.f};
            ahn[i] = f32x4{0.f, 0.f, 0.f, 0.f};
        }
        #pragma unroll
        for (int kk = 0; kk < 2; kk++) {
            const int o0 = r16 * HD + kb + kk * 32 + k8;
            const int o1 = (16 + r16) * HD + kb + kk * 32 + k8;
            bf16x8 x0h = ld8(xH + o0), x0l = ld8(xL + o0);
            bf16x8 x1h = ld8(xH + o1), x1l = ld8(xL + o1);
            bf16x8 y0h = ld8(yH + o0), y0l = ld8(yL + o0);
            bf16x8 y1h = ld8(yH + o1), y1l = ld8(yL + o1);
            arz[0][0] = mfma3(x0h, x0l, wIh[0][kk], wIl[0][kk], arz[0][0]);
            arz[0][0] = mfma3(y0h, y0l, wHh[0][kk], wHl[0][kk], arz[0][0]);
            arz[1][0] = mfma3(x1h, x1l, wIh[0][kk], wIl[0][kk], arz[1][0]);
            arz[1][0] = mfma3(y1h, y1l, wHh[0][kk], wHl[0][kk], arz[1][0]);
            arz[0][1] = mfma3(x0h, x0l, wIh[1][kk], wIl[1][kk], arz[0][1]);
            arz[0][1] = mfma3(y0h, y0l, wHh[1][kk], wHl[1][kk], arz[0][1]);
            arz[1][1] = mfma3(x1h, x1l, wIh[1][kk], wIl[1][kk], arz[1][1]);
            arz[1][1] = mfma3(y1h, y1l, wHh[1][kk], wHl[1][kk], arz[1][1]);
            ain[0] = mfma3(x0h, x0l, wIh[2][kk], wIl[2][kk], ain[0]);
            ain[1] = mfma3(x1h, x1l, wIh[2][kk], wIl[2][kk], ain[1]);
            ahn[0] = mfma3(y0h, y0l, wHh[2][kk], wHl[2][kk], ahn[0]);
            ahn[1] = mfma3(y1h, y1l, wHh[2][kk], wHl[2][kk], ahn[1]);
        }
        red[wid][0][lane] = arz[0][0];
        red[wid][1][lane] = arz[1][0];
        red[wid][2][lane] = arz[0][1];
        red[wid][3][lane] = arz[1][1];
        red[wid][4][lane] = ain[0];
        red[wid][5][lane] = ain[1];
        red[wid][6][lane] = ahn[0];
        red[wid][7][lane] = ahn[1];
        __syncthreads();
        if (wid == 0) {
            f32x4 p[8];
            #pragma unroll
            for (int grp = 0; grp < 8; grp++) {
                f32x4 v = red[0][grp][lane];
                #pragma unroll
                for (int w2 = 1; w2 < 8; w2++) v += red[w2][grp][lane];
                p[grp] = v;
            }
            if (kh == 1) {
                #pragma unroll
                for (int grp = 0; grp < 8; grp++)
                    stc4f((float*)&part[((size_t)blockIdx.x * 8 + grp) * 64 + lane], p[grp]);
                asm volatile("s_waitcnt vmcnt(0)" ::: "memory");
                if (lane == 0)
                    __hip_atomic_store(&flagd[blockIdx.x * BSTR], s, __ATOMIC_RELAXED, __HIP_MEMORY_SCOPE_AGENT);
            } else {
                while (__hip_atomic_load(&flagd[blockIdx.x * BSTR], __ATOMIC_RELAXED, __HIP_MEMORY_SCOPE_AGENT) < s)
                    __builtin_amdgcn_s_sleep(1);
                asm volatile("" ::: "memory");
                #pragma unroll
                for (int grp = 0; grp < 8; grp++)
                    p[grp] += ldc4f((const float*)&part[((size_t)blockIdx.x * 8 + grp) * 64 + lane]);
                const float brr = bih1[j] + bhh1[j];
                const float bzz = bih1[HD + j] + bhh1[HD + j];
                const float bin = bih1[2 * HD + j];
                const float bhn = bhh1[2 * HD + j];
                bf16* wHs = hsHi + (size_t)s * DSLOT + (size_t)NB * HD;
                bf16* wLs = hsLo + (size_t)s * DSLOT + (size_t)NB * HD;
                const int64_t h1b = (int64_t)(p1 * NLAY + 1) * NB * HD;
                #pragma unroll
                for (int mt = 0; mt < 2; mt++)
                    #pragma unroll
                    for (int r = 0; r < 4; r++) {
                        const int b = mt * 16 + (lane >> 4) * 4 + r;
                        const float rg = sigm(p[0 + mt][r] + brr);
                        const float zg = sigm(p[2 + mt][r] + bzz);
                        const float ng = tanhf(p[4 + mt][r] + bin + rg * (p[6 + mt][r] + bhn));
                        const float hold = h32[h1b + (int64_t)b * HD + j];
                        const float hnew = (1.f - zg) * ng + zg * hold;
                        bf16 hh = f2b(hnew);
                        bf16 hl = f2b(hnew - b2f(hh));
                        h32[(int64_t)(np1 * NLAY + 1) * NB * HD + (int64_t)b * HD + j] = hnew;
                        const int lo_ = b * HD + j;
                        wHs[lo_] = hh;
                        wLs[lo_] = hl;
                        const int64_t ro = ((int64_t)t * NB + b) * HD + j;
                        rnnHi[ro] = hh;
                        rnnLo[ro] = hl;
                    }
            }
        }
    }
}

// =====================================================================
__global__ __launch_bounds__(64) void softmax_k(const float* __restrict__ sc,
                                                float* __restrict__ aout)
{
    const int row = blockIdx.x, l = threadIdx.x;
    float v0 = sc[row * LI + l], v1 = sc[row * LI + 64 + l];
    float m = fmaxf(v0, v1);
    #pragma unroll
    for (int o = 32; o > 0; o >>= 1) m = fmaxf(m, __shfl_xor(m, o));
    float e0 = expf(v0 - m), e1 = expf(v1 - m);
    float s = e0 + e1;
    #pragma unroll
    for (int o = 32; o > 0; o >>= 1) s += __shfl_xor(s, o);
    const float inv = 1.f / s;
    aout[row * LI + l] = e0 * inv;
    aout[row * LI + 64 + l] = e1 * inv;
}

// ctx from hi/lo enc outputs -> hi/lo JIN
__global__ __launch_bounds__(256) void ctx2_k(const float* __restrict__ at,
                                              const bf16* __restrict__ eHi,
                                              const bf16* __restrict__ eLo,
                                              bf16* __restrict__ jHi,
                                              bf16* __restrict__ jLo)
{
    const int b = blockIdx.y, h0 = blockIdx.x * 128;
    __shared__ __align__(16) float al[LO][LI];
    for (int i = threadIdx.x; i < LO * LI; i += 256) {
        const int to = i >> 7, ti = i & 127;
        al[to][ti] = at[(to * NB + b) * LI + ti];
    }
    __syncthreads();
    const int hc = h0 + (threadIdx.x & 127);
    const int rh = threadIdx.x >> 7;
    float acc[32];
    #pragma unroll
    for (int i = 0; i < 32; i++) acc[i] = 0.f;
    for (int t = 0; t < LI; t++) {
        const int64_t eo = ((int64_t)t * NB + b) * HD + hc;
        const float ev = b2f(eHi[eo]) + b2f(eLo[eo]);
        #pragma unroll
        for (int i = 0; i < 32; i++) acc[i] += ev * al[rh * 32 + i][t];
    }
    #pragma unroll
    for (int i = 0; i < 32; i++) {
        const int64_t jo = ((int64_t)(rh * 32 + i) * NB + b) * (2 * HD) + hc;
        bf16 hh = f2b(acc[i]);
        jHi[jo] = hh;
        jLo[jo] = f2b(acc[i] - b2f(hh));
    }
}

// copy RNN hi/lo into JIN[:, HD:2HD]
__global__ void rnncopy2_k(const bf16* __restrict__ rHi, const bf16* __restrict__ rLo,
                           bf16* __restrict__ jHi, bf16* __restrict__ jLo)
{
    const int idx = blockIdx.x * 256 + threadIdx.x;
    const int row = idx >> 8;
    const int c = idx & 255;
    ((uint2*)jHi)[(int64_t)row * 512 + 256 + c] = ((const uint2*)rHi)[idx];
    ((uint2*)jLo)[(int64_t)row * 512 + 256 + c] = ((const uint2*)rLo)[idx];
}

// =====================================================================
extern "C" void kernel_launch(void* const* d_in, const int* in_sizes, int n_in,
                              void* d_out, int out_size, void* d_ws, size_t ws_size,
                              hipStream_t stream)
{
    (void)in_sizes; (void)n_in; (void)out_size;
    const int*   in_tok   = (const int*)d_in[0];
    const int*   out_tok  = (const int*)d_in[2];
    const float* enc_emb  = (const float*)d_in[4];
    const float* enc_wih  = (const float*)d_in[5];
    const float* enc_whh  = (const float*)d_in[6];
    const float* enc_bih  = (const float*)d_in[7];
    const float* enc_bhh  = (const float*)d_in[8];
    const float* dec_emb  = (const float*)d_in[9];
    const float* dec_wih  = (const float*)d_in[10];
    const float* dec_whh  = (const float*)d_in[11];
    const float* dec_bih  = (const float*)d_in[12];
    const float* dec_bhh  = (const float*)d_in[13];
    const float* attn_W   = (const float*)d_in[14];
    const float* joiner_W = (const float*)d_in[15];
    const float* joiner_b = (const float*)d_in[16];
    const float* proj_W   = (const float*)d_in[17];
    const float* proj_b   = (const float*)d_in[18];
    float* logits   = (float*)d_out;
    float* attn_out = logits + (size_t)LO * NB * NV;

    const size_t MB = 1ull << 20;
    char* o = (char*)d_out;   // logits region = 250 MiB fp32
    bf16* XB0HI  = (bf16*)(o);               // 8 MiB (dead after L0 gi)
    bf16* XB0LO  = (bf16*)(o + 8 * MB);      // 8 MiB
    bf16* XB1HI  = (bf16*)(o + 16 * MB);     // 8 MiB
    bf16* XB1LO  = (bf16*)(o + 24 * MB);     // 8 MiB
    bf16* EOUTHI = (bf16*)(o + 32 * MB);     // 8 MiB (alive until ctx)
    bf16* EOUTLO = (bf16*)(o + 40 * MB);     // 8 MiB
    float* PENC  = (float*)(o + 48 * MB);    // 16 MiB fp32
    float* GI    = (float*)(o + 64 * MB);    // 48 MiB fp32
    float* DGI0  = (float*)(o + 112 * MB);   // 24 MiB fp32
    bf16* ENCH_HI = (bf16*)(o + 136 * MB);   // 8 MiB per-step slots
    bf16* ENCH_LO = (bf16*)(o + 144 * MB);   // 8 MiB
    bf16* JINHI  = (bf16*)(o + 152 * MB);    // 8 MiB (written post-dec)
    bf16* JINLO  = (bf16*)(o + 160 * MB);    // 8 MiB
    bf16* RNNHI  = (bf16*)(o + 168 * MB);    // 4 MiB
    bf16* RNNLO  = (bf16*)(o + 172 * MB);    // 4 MiB
    float* SC    = (float*)(o + 176 * MB);   // 1 MiB
    bf16* WencHi = (bf16*)(o + 177 * MB);    // 6 MiB
    bf16* WencLo = (bf16*)(o + 183 * MB);    // 6 MiB
    bf16* WdhHi  = (bf16*)(o + 189 * MB);    // 12 MiB
    bf16* WdhLo  = (bf16*)(o + 201 * MB);    // 12 MiB
    bf16* Wih1Hi = (bf16*)(o + 213 * MB);    // 6 MiB
    bf16* Wih1Lo = (bf16*)(o + 219 * MB);    // 6 MiB
    char* ba     = o + 225 * MB;             // 1 MiB: FL_E + FLAGD
    f32x4* PART  = (f32x4*)(o + 228 * MB);   // 0.5 MiB
    bf16* DEMBHI = (bf16*)(o + 229 * MB);    // 4 MiB
    bf16* DEMBLO = (bf16*)(o + 233 * MB);    // 4 MiB
    bf16* WATTB  = (bf16*)(o + 237 * MB);    // 2 MiB attn_W bf16
    bf16* WJOINB = (bf16*)(o + 239 * MB);    // 4 MiB joiner_W bf16
    bf16* WDIH0B = (bf16*)(o + 243 * MB);    // 6 MiB dec_wih[0] bf16 -> 249
    bf16* DECH_HI = XB0HI;                   // dec per-step slots (XB0 dead)
    bf16* DECH_LO = JINHI;                   // (JIN written post-dec)

    char* w = (char*)d_ws;
    bf16* VECSHI = (bf16*)(w);                        // 4 MiB
    bf16* VECSLO = (bf16*)(w + 4 * MB);               // 4 MiB
    float* EH32  = (float*)(w + 8 * MB);              // 512 KiB
    float* DH32  = (float*)(w + 8 * MB + 524288);     // 512 KiB
    const bool bigws = (ws_size >= (size_t)80 * MB);
    bf16* PROJW = (bf16*)(w + 12 * MB);               // 62.5 MiB if bigws

    int* FL_E  = (int*)(ba);                 // 64 x 8KB = 512 KiB
    int* FLAGD = (int*)(ba + 512 * 1024);    // 64 x 8KB = 512 KiB

    hipMemsetAsync(ba, 0, 1 * MB, stream);
    hipMemsetAsync(ENCH_HI, 0, (size_t)ESLOT * 2, stream);   // enc slot 0 = zeros
    hipMemsetAsync(ENCH_LO, 0, (size_t)ESLOT * 2, stream);

    // ---- pre-split recurrent weights (hi/lo) + GEMM weights (bf16) ----
    const int nEnc = NLAY * 2 * 3 * HHD * HHD;
    const int nDhh = NLAY * 3 * HD * HD;
    const int nIh1 = 3 * HD * HD;
    presplit_k<<<dim3((nEnc + 255) / 256), dim3(256), 0, stream>>>(enc_whh, WencHi, WencLo, nEnc);
    presplit_k<<<dim3((nDhh + 255) / 256), dim3(256), 0, stream>>>(dec_whh, WdhHi, WdhLo, nDhh);
    presplit_k<<<dim3((nIh1 + 255) / 256), dim3(256), 0, stream>>>(dec_wih + (size_t)3 * HD * HD, Wih1Hi, Wih1Lo, nIh1);
    presplitH_k<<<dim3((HD * HD + 255) / 256), dim3(256), 0, stream>>>(attn_W, WATTB, HD * HD);
    presplitH_k<<<dim3((HD * 2 * HD + 255) / 256), dim3(256), 0, stream>>>(joiner_W, WJOINB, HD * 2 * HD);
    presplitH_k<<<dim3((3 * HD * HD + 255) / 256), dim3(256), 0, stream>>>(dec_wih, WDIH0B, 3 * HD * HD);
    if (bigws)
        presplitH_k<<<dim3((NV * HD + 255) / 256), dim3(256), 0, stream>>>(proj_W, PROJW, NV * HD);

    // ---- decoder prep (bf16-W GEMM, m-major) ----
    embed2_k<<<dim3(LO * NB), dim3(256), 0, stream>>>(out_tok, dec_emb, DEMBHI, DEMBLO, 1);
    gemmBW_k<128, true, false, 0, 1><<<dim3(LO * NB / 128, 3 * HD / 128, 1), 256, 0, stream>>>(
        DEMBHI, DEMBLO, HD, 0, WDIH0B, HD, 0,
        DGI0, nullptr, nullptr, 3 * HD, 0, dec_bih, 0, HD);

    // ---- encoder (persistent, all-to-all hot-spin barrier) ----
    embed2_k<<<dim3(LI * NB), dim3(256), 0, stream>>>(in_tok, enc_emb, XB0HI, XB0LO, 0);
    for (int l = 0; l < NLAY; l++) {
        const bf16* XinH = l ? XB1HI : XB0HI;
        const bf16* XinL = l ? XB1LO : XB0LO;
        bf16* YoH = l ? EOUTHI : XB1HI;
        bf16* YoL = l ? EOUTLO : XB1LO;
        hipMemsetAsync(EH32, 0, (size_t)2 * 2 * NB * HHD * 4, stream);
        gemmWf_k<128, true, false, 0, 1><<<dim3(LI * NB / 128, 3 * HHD / 128, 2), 256, 0, stream>>>(
            XinH, XinL, HD, 0,
            enc_wih + (size_t)l * 2 * 3 * HHD * HD, HD, (int64_t)3 * HHD * HD,
            GI, nullptr, nullptr, 3 * HHD, (int64_t)LI * NB * 3 * HHD,
            enc_bih + l * 2 * 3 * HHD, 3 * HHD, HD);
        enc_persist_k<<<dim3(HHD / 16, 2), dim3(256), 0, stream>>>(
            GI,
            WencHi + (size_t)l * 2 * 3 * HHD * HHD,
            WencLo + (size_t)l * 2 * 3 * HHD * HHD,
            enc_bhh + l * 2 * 3 * HHD,
            EH32, ENCH_HI, ENCH_LO, YoH, YoL,
            DH32 + (size_t)l * NB * HD,
            DECH_HI + (size_t)l * NB * HD,
            DECH_LO + (size_t)l * NB * HD,
            FL_E);
        if (l == 0) hipMemsetAsync(FL_E, 0, 512 * 1024, stream);
    }

    // proj_enc = enc_outputs @ attn_W^T (bf16 W, m-major)
    gemmBW_k<128, false, false, 0, 1><<<dim3(LI * NB / 128, HD / 128, 1), 256, 0, stream>>>(
        EOUTHI, EOUTLO, HD, 0, WATTB, HD, 0,
        PENC, nullptr, nullptr, HD, 0, nullptr, 0, HD);

    // ---- decoder recurrence: 65 per-step launches ----
    for (int s = 0; s <= LO; s++)
        dec_step_k<<<dim3(HD / 16, 3), dim3(512), 0, stream>>>(
            DGI0,
            Wih1Hi, Wih1Lo,
            WdhHi, WdhLo,
            WdhHi + (size_t)3 * HD * HD, WdhLo + (size_t)3 * HD * HD,
            dec_bih + 3 * HD, dec_bhh, dec_bhh + 3 * HD,
            DH32, DECH_HI, DECH_LO, RNNHI, RNNLO, PART, FLAGD, s);

    // ---- batched epilogue ----
    gemmWf_k<64, false, false, 0, 0><<<dim3(1, 1, NB), 256, 0, stream>>>(
        RNNHI, RNNLO, (int64_t)NB * HD, HD, PENC, (int64_t)NB * HD, HD,
        SC, nullptr, nullptr, (int64_t)NB * LI, LI, nullptr, 0, HD);
    softmax_k<<<dim3(LO * NB), dim3(64), 0, stream>>>(SC, attn_out);
    ctx2_k<<<dim3(HD / 128, NB), dim3(256), 0, stream>>>(attn_out, EOUTHI, EOUTLO, JINHI, JINLO);
    rnncopy2_k<<<dim3(LO * NB * HD / 4 / 256), dim3(256), 0, stream>>>(RNNHI, RNNLO, JINHI, JINLO);
    gemmBW_k<128, true, true, 1, 1><<<dim3(LO * NB / 128, HD / 128, 1), 256, 0, stream>>>(
        JINHI, JINLO, 2 * HD, 0, WJOINB, 2 * HD, 0,
        nullptr, VECSHI, VECSLO, HD, 0, joiner_b, 0, 2 * HD);
    // logits GEMM (m-major): bf16 W from d_ws if it fits, else fp32.
    if (bigws) {
        gemmBW_k<128, true, false, 0, 1><<<dim3(LO * NB / 128, NV / 128, 1), 256, 0, stream>>>(
            VECSHI, VECSLO, HD, 0, PROJW, HD, 0,
            logits, nullptr, nullptr, NV, 0, proj_b, 0, HD);
    } else {
        gemmWf_k<128, true, false, 0, 1><<<dim3(LO * NB / 128, NV / 128, 1), 256, 0, stream>>>(
            VECSHI, VECSLO, HD, 0, proj_W, HD, 0,
            logits, nullptr, nullptr, NV, 0, proj_b, 0, HD);
    }
}

// Round 19
// 3110.192 us; speedup vs baseline: 1.7356x; 1.3195x over previous
//
#include <hip/hip_runtime.h>
#include <hip/hip_bf16.h>
#include <stdint.h>

// ---- problem constants ----
constexpr int LI   = 128;    // L_IN
constexpr int LO   = 64;     // L_OUT
constexpr int NB   = 32;     // batch
constexpr int HD   = 1024;   // H
constexpr int HHD  = 512;    // HH
constexpr int NLAY = 2;
constexpr int NV   = 32000;  // V_OUT
constexpr int SOST = 1;

// Round-19 (on passing round-18): (1) encoder epilogue DISTRIBUTED across
// all 4 waves (was serialized on wave0) with gi/h32 operands prefetched
// before the K-loop -> shorter critical path per step; (2) logits GEMM
// drops the A-lo split term (NOLO) -- halves the largest GEMM's MFMA work,
// expected +~2e-4 error (budget 9.77e-4 vs 2.79e-3 threshold).

typedef __hip_bfloat16 bf16;
typedef __attribute__((ext_vector_type(8))) short bf16x8;
typedef __attribute__((ext_vector_type(4))) float f32x4;
typedef unsigned long long u64;

constexpr int BSTR = 2048;   // flag stride in ints = 8 KB
constexpr int ESLOT = 2 * NB * HHD;     // enc per-step slot (elems)
constexpr int DSLOT = NLAY * NB * HD;   // dec per-step slot (elems)

__device__ __forceinline__ float b2f(bf16 x) { return __bfloat162float(x); }
__device__ __forceinline__ bf16  f2b(float x) { return __float2bfloat16(x); }
__device__ __forceinline__ float sigm(float x) { return 1.0f / (1.0f + expf(-x)); }

__device__ __forceinline__ f32x4 mfma(bf16x8 a, bf16x8 b, f32x4 c) {
    return __builtin_amdgcn_mfma_f32_16x16x32_bf16(a, b, c, 0, 0, 0);
}
__device__ __forceinline__ f32x4 mfma3(bf16x8 ah, bf16x8 al, bf16x8 bh, bf16x8 bl, f32x4 c) {
    c = mfma(ah, bh, c);
    c = mfma(ah, bl, c);
    c = mfma(al, bh, c);
    return c;
}
__device__ __forceinline__ bf16x8 ld8(const bf16* p) { return *(const bf16x8*)p; }

// async global->LDS, 16B per lane; LDS base wave-uniform
__device__ __forceinline__ void g2l16(const void* g, void* l) {
    __builtin_amdgcn_global_load_lds(
        (const __attribute__((address_space(1))) unsigned int*)g,
        (__attribute__((address_space(3))) unsigned int*)l,
        16, 0, 0);
}

// ---- coherent (agent/L3) helpers ----
__device__ __forceinline__ void stc2(bf16* p, bf16 a, bf16 b) {
    unsigned v = (unsigned)*(const unsigned short*)&a |
                 ((unsigned)*(const unsigned short*)&b << 16);
    __hip_atomic_store((unsigned*)p, v, __ATOMIC_RELAXED, __HIP_MEMORY_SCOPE_AGENT);
}
__device__ __forceinline__ f32x4 ldc4f(const float* p) {
    union { f32x4 v; u64 q[2]; } u;
    u.q[0] = __hip_atomic_load((const u64*)p,     __ATOMIC_RELAXED, __HIP_MEMORY_SCOPE_AGENT);
    u.q[1] = __hip_atomic_load((const u64*)p + 1, __ATOMIC_RELAXED, __HIP_MEMORY_SCOPE_AGENT);
    return u.v;
}
__device__ __forceinline__ void stc4f(float* p, f32x4 v) {
    union { f32x4 v; u64 q[2]; } u;
    u.v = v;
    __hip_atomic_store((u64*)p,     u.q[0], __ATOMIC_RELAXED, __HIP_MEMORY_SCOPE_AGENT);
    __hip_atomic_store((u64*)p + 1, u.q[1], __ATOMIC_RELAXED, __HIP_MEMORY_SCOPE_AGENT);
}

// ---- all-to-all flag barrier (hot spin). Caller must have drained its
// own stores (all waves) before entry; the entry __syncthreads orders them
// before tid0's flag store.
__device__ __forceinline__ void gbarA(int* __restrict__ flags,
                                      int nblk, int myid, int val) {
    __syncthreads();
    const int tid = threadIdx.x;
    if (tid < 64) {
        if (tid == 0) {
            asm volatile("s_waitcnt vmcnt(0)" ::: "memory");
            __hip_atomic_store(&flags[myid * BSTR], val, __ATOMIC_RELAXED, __HIP_MEMORY_SCOPE_AGENT);
        }
        bool done = false;
        while (!done) {
            int v = (tid < nblk)
                ? __hip_atomic_load(&flags[tid * BSTR], __ATOMIC_RELAXED, __HIP_MEMORY_SCOPE_AGENT)
                : val;
            done = __all(v >= val);
        }
        asm volatile("" ::: "memory");
    }
    __syncthreads();
}

// =====================================================================
// GEMM (fp32 W, rounded to bf16 in-register). SW: m-major. NOLO: drop A-lo.
// =====================================================================
template<int BM, bool BIAS, bool TANH, int OM, int SW, bool NOLO = false>
__global__ __launch_bounds__(256) void gemmWf_k(
    const bf16* __restrict__ Ahi, const bf16* __restrict__ Alo,
    int64_t lda, int64_t sA,
    const float* __restrict__ W, int64_t ldw, int64_t sW,
    float* __restrict__ C, bf16* __restrict__ Chi, bf16* __restrict__ Clo,
    int64_t ldc, int64_t sC,
    const float* __restrict__ bias, int64_t sBias,
    int K)
{
    constexpr int FM = BM / 32;
    __shared__ __align__(16) bf16 Ah[BM * 32], Al[BM * 32];
    __shared__ __align__(16) bf16 Wl[128 * 32];
    const int z    = blockIdx.z;
    const bf16* Abh = Ahi + (int64_t)z * sA;
    const bf16* Abl = Alo + (int64_t)z * sA;
    const float* Wb = W + (int64_t)z * sW;
    const int n0   = (SW ? blockIdx.y : blockIdx.x) * 128;
    const int m0   = (SW ? blockIdx.x : blockIdx.y) * BM;
    const int tid  = threadIdx.x;
    const int lane = tid & 63, wid = tid >> 6;
    const int wm   = wid >> 1, wn = wid & 1;
    const int srow = lane >> 2;
    const int skb  = (lane & 3) * 8;
    const int r16  = lane & 15;
    const int k8   = (lane >> 4) * 8;

    f32x4 acc[FM][4];
    #pragma unroll
    for (int i = 0; i < FM; i++)
        #pragma unroll
        for (int j = 0; j < 4; j++)
            acc[i][j] = f32x4{0.f, 0.f, 0.f, 0.f};

    for (int k0 = 0; k0 < K; k0 += 32) {
        for (int c = wid; c < BM / 16; c += 4) {
            g2l16(Abh + (int64_t)(m0 + c * 16 + srow) * lda + k0 + skb, Ah + c * 512);
            if constexpr (!NOLO)
                g2l16(Abl + (int64_t)(m0 + c * 16 + srow) * lda + k0 + skb, Al + c * 512);
        }
        for (int c = wid; c < 8; c += 4) {
            const float* wp = Wb + (int64_t)(n0 + c * 16 + srow) * ldw + k0 + skb;
            bf16x8 wv;
            #pragma unroll
            for (int jj = 0; jj < 8; jj++) ((bf16*)&wv)[jj] = f2b(wp[jj]);
            *(bf16x8*)(Wl + c * 512 + lane * 8) = wv;
        }
        __syncthreads();
        bf16x8 afh[FM], afl[FM], wf[4];
        #pragma unroll
        for (int mt = 0; mt < FM; mt++) {
            const int off = (wm * (BM / 2) + mt * 16 + r16) * 32 + k8;
            afh[mt] = ld8(Ah + off);
            if constexpr (!NOLO) afl[mt] = ld8(Al + off);
        }
        #pragma unroll
        for (int nt = 0; nt < 4; nt++)
            wf[nt] = ld8(Wl + (wn * 64 + nt * 16 + r16) * 32 + k8);
        #pragma unroll
        for (int mt = 0; mt < FM; mt++)
            #pragma unroll
            for (int nt = 0; nt < 4; nt++) {
                acc[mt][nt] = mfma(afh[mt], wf[nt], acc[mt][nt]);
                if constexpr (!NOLO)
                    acc[mt][nt] = mfma(afl[mt], wf[nt], acc[mt][nt]);
            }
        __syncthreads();
    }
    #pragma unroll
    for (int nt = 0; nt < 4; nt++) {
        const int n = n0 + wn * 64 + nt * 16 + r16;
        float bv = 0.f;
        if constexpr (BIAS) bv = bias[(int64_t)z * sBias + n];
        #pragma unroll
        for (int mt = 0; mt < FM; mt++) {
            const int mb = m0 + wm * (BM / 2) + mt * 16 + (lane >> 4) * 4;
            #pragma unroll
            for (int r = 0; r < 4; r++) {
                float v = acc[mt][nt][r] + bv;
                if constexpr (TANH) v = tanhf(v);
                const int64_t co = (int64_t)z * sC + (int64_t)(mb + r) * ldc + n;
                if constexpr (OM == 0) {
                    C[co] = v;
                } else {
                    bf16 hh = f2b(v);
                    Chi[co] = hh;
                    Clo[co] = f2b(v - b2f(hh));
                }
            }
        }
    }
}

// =====================================================================
// GEMM with PRE-SPLIT bf16 W. SW: m-major. NOLO: drop A-lo.
// =====================================================================
template<int BM, bool BIAS, bool TANH, int OM, int SW, bool NOLO = false>
__global__ __launch_bounds__(256) void gemmBW_k(
    const bf16* __restrict__ Ahi, const bf16* __restrict__ Alo,
    int64_t lda, int64_t sA,
    const bf16* __restrict__ W, int64_t ldw, int64_t sW,
    float* __restrict__ C, bf16* __restrict__ Chi, bf16* __restrict__ Clo,
    int64_t ldc, int64_t sC,
    const float* __restrict__ bias, int64_t sBias,
    int K)
{
    constexpr int FM = BM / 32;
    __shared__ __align__(16) bf16 Ah[BM * 32], Al[BM * 32];
    __shared__ __align__(16) bf16 Wl[128 * 32];
    const int z    = blockIdx.z;
    const bf16* Abh = Ahi + (int64_t)z * sA;
    const bf16* Abl = Alo + (int64_t)z * sA;
    const bf16* Wb = W + (int64_t)z * sW;
    const int n0   = (SW ? blockIdx.y : blockIdx.x) * 128;
    const int m0   = (SW ? blockIdx.x : blockIdx.y) * BM;
    const int tid  = threadIdx.x;
    const int lane = tid & 63, wid = tid >> 6;
    const int wm   = wid >> 1, wn = wid & 1;
    const int srow = lane >> 2;
    const int skb  = (lane & 3) * 8;
    const int r16  = lane & 15;
    const int k8   = (lane >> 4) * 8;

    f32x4 acc[FM][4];
    #pragma unroll
    for (int i = 0; i < FM; i++)
        #pragma unroll
        for (int j = 0; j < 4; j++)
            acc[i][j] = f32x4{0.f, 0.f, 0.f, 0.f};

    for (int k0 = 0; k0 < K; k0 += 32) {
        for (int c = wid; c < BM / 16; c += 4) {
            g2l16(Abh + (int64_t)(m0 + c * 16 + srow) * lda + k0 + skb, Ah + c * 512);
            if constexpr (!NOLO)
                g2l16(Abl + (int64_t)(m0 + c * 16 + srow) * lda + k0 + skb, Al + c * 512);
        }
        for (int c = wid; c < 8; c += 4)
            g2l16(Wb + (int64_t)(n0 + c * 16 + srow) * ldw + k0 + skb, Wl + c * 512);
        __syncthreads();
        bf16x8 afh[FM], afl[FM], wf[4];
        #pragma unroll
        for (int mt = 0; mt < FM; mt++) {
            const int off = (wm * (BM / 2) + mt * 16 + r16) * 32 + k8;
            afh[mt] = ld8(Ah + off);
            if constexpr (!NOLO) afl[mt] = ld8(Al + off);
        }
        #pragma unroll
        for (int nt = 0; nt < 4; nt++)
            wf[nt] = ld8(Wl + (wn * 64 + nt * 16 + r16) * 32 + k8);
        #pragma unroll
        for (int mt = 0; mt < FM; mt++)
            #pragma unroll
            for (int nt = 0; nt < 4; nt++) {
                acc[mt][nt] = mfma(afh[mt], wf[nt], acc[mt][nt]);
                if constexpr (!NOLO)
                    acc[mt][nt] = mfma(afl[mt], wf[nt], acc[mt][nt]);
            }
        __syncthreads();
    }
    #pragma unroll
    for (int nt = 0; nt < 4; nt++) {
        const int n = n0 + wn * 64 + nt * 16 + r16;
        float bv = 0.f;
        if constexpr (BIAS) bv = bias[(int64_t)z * sBias + n];
        #pragma unroll
        for (int mt = 0; mt < FM; mt++) {
            const int mb = m0 + wm * (BM / 2) + mt * 16 + (lane >> 4) * 4;
            #pragma unroll
            for (int r = 0; r < 4; r++) {
                float v = acc[mt][nt][r] + bv;
                if constexpr (TANH) v = tanhf(v);
                const int64_t co = (int64_t)z * sC + (int64_t)(mb + r) * ldc + n;
                if constexpr (OM == 0) {
                    C[co] = v;
                } else {
                    bf16 hh = f2b(v);
                    Chi[co] = hh;
                    Clo[co] = f2b(v - b2f(hh));
                }
            }
        }
    }
}

__global__ void presplit_k(const float* __restrict__ x, bf16* __restrict__ hi,
                           bf16* __restrict__ lo, int n)
{
    const int i = blockIdx.x * 256 + threadIdx.x;
    if (i < n) {
        float v = x[i];
        bf16 h = f2b(v);
        hi[i] = h;
        lo[i] = f2b(v - b2f(h));
    }
}

// fp32 -> single rounded bf16
__global__ void presplitH_k(const float* __restrict__ x, bf16* __restrict__ hi, int n)
{
    const int i = blockIdx.x * 256 + threadIdx.x;
    if (i < n) hi[i] = f2b(x[i]);
}

// embed writing hi/lo pair
__global__ void embed2_k(const int* __restrict__ toks, const float* __restrict__ tab,
                         bf16* __restrict__ ohi, bf16* __restrict__ olo, int shifted)
{
    const int row = blockIdx.x;
    int tok;
    if (shifted) {
        const int t = row / NB, b = row - t * NB;
        tok = (t == 0) ? SOST : toks[(t - 1) * NB + b];
    } else {
        tok = toks[row];
    }
    const float4 v = ((const float4*)(tab + (int64_t)tok * HD))[threadIdx.x];
    bf16 h0 = f2b(v.x), h1 = f2b(v.y), h2 = f2b(v.z), h3 = f2b(v.w);
    bf16 hv[4] = {h0, h1, h2, h3};
    bf16 lv[4] = {f2b(v.x - b2f(h0)), f2b(v.y - b2f(h1)),
                  f2b(v.z - b2f(h2)), f2b(v.w - b2f(h3))};
    *(uint2*)(ohi + (int64_t)row * HD + threadIdx.x * 4) = *(uint2*)hv;
    *(uint2*)(olo + (int64_t)row * HD + threadIdx.x * 4) = *(uint2*)lv;
}

// =====================================================================
// Persistent encoder layer. Epilogue DISTRIBUTED across 4 waves:
// wave w handles (mt,r) values 2w, 2w+1; gi/h32 operands prefetched
// before the K-loop; all waves drain before the flag barrier.
// Grid (HHD/16=32, 2 dirs) x 256 thr.
// =====================================================================
__global__ __launch_bounds__(256, 1) void enc_persist_k(
    const float* __restrict__ gi,
    const bf16* __restrict__ whhHi,
    const bf16* __restrict__ whhLo,
    const float* __restrict__ bhh,
    float* __restrict__ h32,
    bf16* __restrict__ hsHi, bf16* __restrict__ hsLo,
    bf16* __restrict__ yHi, bf16* __restrict__ yLo,
    float* __restrict__ dh32, bf16* __restrict__ dhHi, bf16* __restrict__ dhLo,
    int* __restrict__ flags)
{
    __shared__ f32x4 red[4][6][64];
    const int d = blockIdx.y;
    const int j0 = blockIdx.x * 16;
    const int tid = threadIdx.x;
    const int lane = tid & 63, wid = tid >> 6;
    const int r16 = lane & 15, k8 = (lane >> 4) * 8;
    const int kq = wid * 128;
    const bf16* WdH = whhHi + (int64_t)d * 3 * HHD * HHD;
    const bf16* WdL = whhLo + (int64_t)d * 3 * HHD * HHD;
    const int j = j0 + r16;
    const int myid = d * 32 + blockIdx.x;

    bf16x8 wh[3][4], wl[3][4];
    #pragma unroll
    for (int g = 0; g < 3; g++)
        #pragma unroll
        for (int kk = 0; kk < 4; kk++) {
            const int64_t wo = (int64_t)(g * HHD + j0 + r16) * HHD + kq + kk * 32 + k8;
            wh[g][kk] = ld8(WdH + wo);
            wl[g][kk] = ld8(WdL + wo);
        }
    const float br = bhh[d * 3 * HHD + j];
    const float bz = bhh[d * 3 * HHD + HHD + j];
    const float bn = bhh[d * 3 * HHD + 2 * HHD + j];

    // this wave's two (mt,r) values: val = wid*2 + k
    int bv_[2];
    #pragma unroll
    for (int k = 0; k < 2; k++) {
        const int val = wid * 2 + k;
        const int mt = val >> 2, r = val & 3;
        bv_[k] = mt * 16 + (lane >> 4) * 4 + r;
    }

    for (int s = 0; s < LI; s++) {
        const int t = d ? (LI - 1 - s) : s;
        const int par = s & 1, npar = par ^ 1;
        const bf16* rH = hsHi + (size_t)s * ESLOT + (size_t)d * NB * HHD;
        const bf16* rL = hsLo + (size_t)s * ESLOT + (size_t)d * NB * HHD;

        // prefetch gi + hold for this wave's values (hidden under MFMA)
        const float* gid = gi + ((int64_t)d * LI * NB + (int64_t)t * NB) * (3 * HHD);
        const int64_t hbase = (int64_t)(par * 2 + d) * NB * HHD;
        float pir[2], piz[2], pin[2], phold[2];
        #pragma unroll
        for (int k = 0; k < 2; k++) {
            const int b = bv_[k];
            pir[k]   = gid[b * 3 * HHD + j];
            piz[k]   = gid[b * 3 * HHD + HHD + j];
            pin[k]   = gid[b * 3 * HHD + 2 * HHD + j];
            phold[k] = h32[hbase + (int64_t)b * HHD + j];
        }

        f32x4 acc[2][3];
        #pragma unroll
        for (int m = 0; m < 2; m++)
            #pragma unroll
            for (int g = 0; g < 3; g++) acc[m][g] = f32x4{0.f, 0.f, 0.f, 0.f};

        #pragma unroll
        for (int kk = 0; kk < 4; kk++) {
            const int o0 = r16 * HHD + kq + kk * 32 + k8;
            const int o1 = (16 + r16) * HHD + kq + kk * 32 + k8;
            bf16x8 a0h = ld8(rH + o0), a0l = ld8(rL + o0);
            bf16x8 a1h = ld8(rH + o1), a1l = ld8(rL + o1);
            #pragma unroll
            for (int g = 0; g < 3; g++) {
                acc[0][g] = mfma3(a0h, a0l, wh[g][kk], wl[g][kk], acc[0][g]);
                acc[1][g] = mfma3(a1h, a1l, wh[g][kk], wl[g][kk], acc[1][g]);
            }
        }
        #pragma unroll
        for (int m = 0; m < 2; m++)
            #pragma unroll
            for (int g = 0; g < 3; g++)
                red[wid][m * 3 + g][lane] = acc[m][g];
        __syncthreads();

        // distributed cell epilogue: wave w -> values 2w, 2w+1
        float hnv[2];
        bf16* wH = hsHi + (size_t)(s + 1) * ESLOT + (size_t)d * NB * HHD;
        bf16* wL = hsLo + (size_t)(s + 1) * ESLOT + (size_t)d * NB * HHD;
        #pragma unroll
        for (int k = 0; k < 2; k++) {
            const int val = wid * 2 + k;
            const int mt = val >> 2, r = val & 3;
            const int b = bv_[k];
            const float ar = red[0][mt * 3 + 0][lane][r] + red[1][mt * 3 + 0][lane][r]
                           + red[2][mt * 3 + 0][lane][r] + red[3][mt * 3 + 0][lane][r];
            const float az = red[0][mt * 3 + 1][lane][r] + red[1][mt * 3 + 1][lane][r]
                           + red[2][mt * 3 + 1][lane][r] + red[3][mt * 3 + 1][lane][r];
            const float an = red[0][mt * 3 + 2][lane][r] + red[1][mt * 3 + 2][lane][r]
                           + red[2][mt * 3 + 2][lane][r] + red[3][mt * 3 + 2][lane][r];
            const float rg = sigm(pir[k] + ar + br);
            const float zg = sigm(piz[k] + az + bz);
            const float ng = tanhf(pin[k] + an + rg * (an * 0.f + an + bn - an));   // = tanhf(pin + an_h)
            // NOTE: expression kept simple below; see hnv computation
            const float ng2 = tanhf(pin[k] + rg * (an + bn));
            (void)ng;
            const float hnew = (1.f - zg) * ng2 + zg * phold[k];
            hnv[k] = hnew;
            const float hn2 = __shfl_xor(hnew, 1);
            if (s < LI - 1 && !(lane & 1)) {
                bf16 hh = f2b(hnew);
                bf16 hl = f2b(hnew - b2f(hh));
                bf16 hh2 = f2b(hn2);
                bf16 hl2 = f2b(hn2 - b2f(hh2));
                const int lo_ = b * HHD + j;
                stc2(wH + lo_, hh, hh2);
                stc2(wL + lo_, hl, hl2);
            }
        }
        asm volatile("s_waitcnt vmcnt(0)" ::: "memory");
        if (s < LI - 1) gbarA(flags, 64, myid, s + 1);

        // deferred writes (off critical path)
        const int64_t hb2 = (int64_t)(npar * 2 + d) * NB * HHD;
        #pragma unroll
        for (int k = 0; k < 2; k++) {
            const int b = bv_[k];
            const float hnew = hnv[k];
            bf16 hh = f2b(hnew);
            bf16 hl = f2b(hnew - b2f(hh));
            h32[hb2 + (int64_t)b * HHD + j] = hnew;
            const int64_t yo = ((int64_t)t * NB + b) * HD + d * HHD + j;
            yHi[yo] = hh;
            yLo[yo] = hl;
            if (s == LI - 1) {
                const int64_t dof = (int64_t)b * HD + d * HHD + j;
                dh32[dof] = hnew;
                dhHi[dof] = hh;
                dhLo[dof] = hl;
            }
        }
    }
}

// =====================================================================
// Decoder PER-STEP kernel (round-18, passing/unchanged).
// =====================================================================
__global__ __launch_bounds__(512) void dec_step_k(
    const float* __restrict__ gi0,
    const bf16* __restrict__ wih1Hi, const bf16* __restrict__ wih1Lo,
    const bf16* __restrict__ whh0Hi, const bf16* __restrict__ whh0Lo,
    const bf16* __restrict__ whh1Hi, const bf16* __restrict__ whh1Lo,
    const float* __restrict__ bih1,
    const float* __restrict__ bhh0,
    const float* __restrict__ bhh1,
    float* __restrict__ h32,
    bf16* __restrict__ hsHi, bf16* __restrict__ hsLo,
    bf16* __restrict__ rnnHi, bf16* __restrict__ rnnLo,
    f32x4* __restrict__ part,
    int* __restrict__ flagd,
    int s)
{
    __shared__ f32x4 red[8][8][64];
    const int tid = threadIdx.x;
    const int lane = tid & 63, wid = tid >> 6;
    const int r16 = lane & 15, k8 = (lane >> 4) * 8;
    const int j0 = blockIdx.x * 16;
    const int j = j0 + r16;

    if (blockIdx.y == 0) {
        if (s >= LO) return;
        const int t = s, par = t & 1, npar = par ^ 1;
        const int kq = wid * 128;
        bf16x8 wh[3][4], wl[3][4];
        #pragma unroll
        for (int g = 0; g < 3; g++)
            #pragma unroll
            for (int kk = 0; kk < 4; kk++) {
                const int64_t wo = (int64_t)(g * HD + j0 + r16) * HD + kq + kk * 32 + k8;
                wh[g][kk] = ld8(whh0Hi + wo);
                wl[g][kk] = ld8(whh0Lo + wo);
            }
        const bf16* rH = hsHi + (size_t)s * DSLOT;
        const bf16* rL = hsLo + (size_t)s * DSLOT;
        f32x4 acc[2][3];
        #pragma unroll
        for (int m = 0; m < 2; m++)
            #pragma unroll
            for (int g = 0; g < 3; g++) acc[m][g] = f32x4{0.f, 0.f, 0.f, 0.f};
        #pragma unroll
        for (int kk = 0; kk < 4; kk++) {
            const int o0 = r16 * HD + kq + kk * 32 + k8;
            const int o1 = (16 + r16) * HD + kq + kk * 32 + k8;
            bf16x8 a0h = ld8(rH + o0), a0l = ld8(rL + o0);
            bf16x8 a1h = ld8(rH + o1), a1l = ld8(rL + o1);
            #pragma unroll
            for (int g = 0; g < 3; g++) {
                acc[0][g] = mfma3(a0h, a0l, wh[g][kk], wl[g][kk], acc[0][g]);
                acc[1][g] = mfma3(a1h, a1l, wh[g][kk], wl[g][kk], acc[1][g]);
            }
        }
        #pragma unroll
        for (int m = 0; m < 2; m++)
            #pragma unroll
            for (int g = 0; g < 3; g++)
                red[wid][m * 3 + g][lane] = acc[m][g];
        __syncthreads();
        if (wid == 0) {
            const float b0r = bhh0[j], b0z = bhh0[HD + j], b0n = bhh0[2 * HD + j];
            f32x4 a2[2][3];
            #pragma unroll
            for (int m = 0; m < 2; m++)
                #pragma unroll
                for (int g = 0; g < 3; g++) {
                    f32x4 v = red[0][m * 3 + g][lane];
                    #pragma unroll
                    for (int w2 = 1; w2 < 8; w2++) v += red[w2][m * 3 + g][lane];
                    a2[m][g] = v;
                }
            const float* gid = gi0 + (int64_t)t * NB * 3 * HD;
            bf16* wHs = hsHi + (size_t)(s + 1) * DSLOT;
            bf16* wLs = hsLo + (size_t)(s + 1) * DSLOT;
            const int64_t hb = (int64_t)(par * NLAY + 0) * NB * HD;
            #pragma unroll
            for (int mt = 0; mt < 2; mt++)
                #pragma unroll
                for (int r = 0; r < 4; r++) {
                    const int b = mt * 16 + (lane >> 4) * 4 + r;
                    const float ir  = gid[b * 3 * HD + j];
                    const float iz  = gid[b * 3 * HD + HD + j];
                    const float inn = gid[b * 3 * HD + 2 * HD + j];
                    const float rg = sigm(ir + a2[mt][0][r] + b0r);
                    const float zg = sigm(iz + a2[mt][1][r] + b0z);
                    const float ng = tanhf(inn + rg * (a2[mt][2][r] + b0n));
                    const float hold = h32[hb + (int64_t)b * HD + j];
                    const float hnew = (1.f - zg) * ng + zg * hold;
                    bf16 hh = f2b(hnew);
                    bf16 hl = f2b(hnew - b2f(hh));
                    h32[(int64_t)(npar * NLAY + 0) * NB * HD + (int64_t)b * HD + j] = hnew;
                    const int lo_ = b * HD + j;
                    wHs[lo_] = hh;
                    wLs[lo_] = hl;
                }
        }
    } else {
        if (s < 1) return;
        const int t = s - 1;
        const int p1 = t & 1, np1 = p1 ^ 1;
        const int kh = blockIdx.y - 1;
        const int kb = kh * 512 + wid * 64;
        bf16x8 wIh[3][2], wIl[3][2], wHh[3][2], wHl[3][2];
        #pragma unroll
        for (int g = 0; g < 3; g++)
            #pragma unroll
            for (int kk = 0; kk < 2; kk++) {
                const int64_t wo = (int64_t)(g * HD + j0 + r16) * HD + kb + kk * 32 + k8;
                wIh[g][kk] = ld8(wih1Hi + wo);
                wIl[g][kk] = ld8(wih1Lo + wo);
                wHh[g][kk] = ld8(whh1Hi + wo);
                wHl[g][kk] = ld8(whh1Lo + wo);
            }
        const bf16* xH = hsHi + (size_t)s * DSLOT;
        const bf16* xL = hsLo + (size_t)s * DSLOT;
        const bf16* yH = hsHi + (size_t)(s - 1) * DSLOT + (size_t)NB * HD;
        const bf16* yL = hsLo + (size_t)(s - 1) * DSLOT + (size_t)NB * HD;
        f32x4 arz[2][2], ain[2], ahn[2];
        #pragma unroll
        for (int i = 0; i < 2; i++) {
            arz[i][0] = f32x4{0.f, 0.f, 0.f, 0.f};
            arz[i][1] = f32x4{0.f, 0.f, 0.f, 0.f};
            ain[i] = f32x4{0.f, 0.f, 0.f, 0.f};
            ahn[i] = f32x4{0.f, 0.f, 0.f, 0.f};
        }
        #pragma unroll
        for (int kk = 0; kk < 2; kk++) {
            const int o0 = r16 * HD + kb + kk * 32 + k8;
            const int o1 = (16 + r16) * HD + kb + kk * 32 + k8;
            bf16x8 x0h = ld8(xH + o0), x0l = ld8(xL + o0);
            bf16x8 x1h = ld8(xH + o1), x1l = ld8(xL + o1);
            bf16x8 y0h = ld8(yH + o0), y0l = ld8(yL + o0);
            bf16x8 y1h = ld8(yH + o1), y1l = ld8(yL + o1);
            arz[0][0] = mfma3(x0h, x0l, wIh[0][kk], wIl[0][kk], arz[0][0]);
            arz[0][0] = mfma3(y0h, y0l, wHh[0][kk], wHl[0][kk], arz[0][0]);
            arz[1][0] = mfma3(x1h, x1l, wIh[0][kk], wIl[0][kk], arz[1][0]);
            arz[1][0] = mfma3(y1h, y1l, wHh[0][kk], wHl[0][kk], arz[1][0]);
            arz[0][1] = mfma3(x0h, x0l, wIh[1][kk], wIl[1][kk], arz[0][1]);
            arz[0][1] = mfma3(y0h, y0l, wHh[1][kk], wHl[1][kk], arz[0][1]);
            arz[1][1] = mfma3(x1h, x1l, wIh[1][kk], wIl[1][kk], arz[1][1]);
            arz[1][1] = mfma3(y1h, y1l, wHh[1][kk], wHl[1][kk], arz[1][1]);
            ain[0] = mfma3(x0h, x0l, wIh[2][kk], wIl[2][kk], ain[0]);
            ain[1] = mfma3(x1h, x1l, wIh[2][kk], wIl[2][kk], ain[1]);
            ahn[0] = mfma3(y0h, y0l, wHh[2][kk], wHl[2][kk], ahn[0]);
            ahn[1] = mfma3(y1h, y1l, wHh[2][kk], wHl[2][kk], ahn[1]);
        }
        red[wid][0][lane] = arz[0][0];
        red[wid][1][lane] = arz[1][0];
        red[wid][2][lane] = arz[0][1];
        red[wid][3][lane] = arz[1][1];
        red[wid][4][lane] = ain[0];
        red[wid][5][lane] = ain[1];
        red[wid][6][lane] = ahn[0];
        red[wid][7][lane] = ahn[1];
        __syncthreads();
        if (wid == 0) {
            f32x4 p[8];
            #pragma unroll
            for (int grp = 0; grp < 8; grp++) {
                f32x4 v = red[0][grp][lane];
                #pragma unroll
                for (int w2 = 1; w2 < 8; w2++) v += red[w2][grp][lane];
                p[grp] = v;
            }
            if (kh == 1) {
                #pragma unroll
                for (int grp = 0; grp < 8; grp++)
                    stc4f((float*)&part[((size_t)blockIdx.x * 8 + grp) * 64 + lane], p[grp]);
                asm volatile("s_waitcnt vmcnt(0)" ::: "memory");
                if (lane == 0)
                    __hip_atomic_store(&flagd[blockIdx.x * BSTR], s, __ATOMIC_RELAXED, __HIP_MEMORY_SCOPE_AGENT);
            } else {
                while (__hip_atomic_load(&flagd[blockIdx.x * BSTR], __ATOMIC_RELAXED, __HIP_MEMORY_SCOPE_AGENT) < s)
                    __builtin_amdgcn_s_sleep(1);
                asm volatile("" ::: "memory");
                #pragma unroll
                for (int grp = 0; grp < 8; grp++)
                    p[grp] += ldc4f((const float*)&part[((size_t)blockIdx.x * 8 + grp) * 64 + lane]);
                const float brr = bih1[j] + bhh1[j];
                const float bzz = bih1[HD + j] + bhh1[HD + j];
                const float bin = bih1[2 * HD + j];
                const float bhn = bhh1[2 * HD + j];
                bf16* wHs = hsHi + (size_t)s * DSLOT + (size_t)NB * HD;
                bf16* wLs = hsLo + (size_t)s * DSLOT + (size_t)NB * HD;
                const int64_t h1b = (int64_t)(p1 * NLAY + 1) * NB * HD;
                #pragma unroll
                for (int mt = 0; mt < 2; mt++)
                    #pragma unroll
                    for (int r = 0; r < 4; r++) {
                        const int b = mt * 16 + (lane >> 4) * 4 + r;
                        const float rg = sigm(p[0 + mt][r] + brr);
                        const float zg = sigm(p[2 + mt][r] + bzz);
                        const float ng = tanhf(p[4 + mt][r] + bin + rg * (p[6 + mt][r] + bhn));
                        const float hold = h32[h1b + (int64_t)b * HD + j];
                        const float hnew = (1.f - zg) * ng + zg * hold;
                        bf16 hh = f2b(hnew);
                        bf16 hl = f2b(hnew - b2f(hh));
                        h32[(int64_t)(np1 * NLAY + 1) * NB * HD + (int64_t)b * HD + j] = hnew;
                        const int lo_ = b * HD + j;
                        wHs[lo_] = hh;
                        wLs[lo_] = hl;
                        const int64_t ro = ((int64_t)t * NB + b) * HD + j;
                        rnnHi[ro] = hh;
                        rnnLo[ro] = hl;
                    }
            }
        }
    }
}

// =====================================================================
__global__ __launch_bounds__(64) void softmax_k(const float* __restrict__ sc,
                                                float* __restrict__ aout)
{
    const int row = blockIdx.x, l = threadIdx.x;
    float v0 = sc[row * LI + l], v1 = sc[row * LI + 64 + l];
    float m = fmaxf(v0, v1);
    #pragma unroll
    for (int o = 32; o > 0; o >>= 1) m = fmaxf(m, __shfl_xor(m, o));
    float e0 = expf(v0 - m), e1 = expf(v1 - m);
    float s = e0 + e1;
    #pragma unroll
    for (int o = 32; o > 0; o >>= 1) s += __shfl_xor(s, o);
    const float inv = 1.f / s;
    aout[row * LI + l] = e0 * inv;
    aout[row * LI + 64 + l] = e1 * inv;
}

// ctx from hi/lo enc outputs -> hi/lo JIN
__global__ __launch_bounds__(256) void ctx2_k(const float* __restrict__ at,
                                              const bf16* __restrict__ eHi,
                                              const bf16* __restrict__ eLo,
                                              bf16* __restrict__ jHi,
                                              bf16* __restrict__ jLo)
{
    const int b = blockIdx.y, h0 = blockIdx.x * 128;
    __shared__ __align__(16) float al[LO][LI];
    for (int i = threadIdx.x; i < LO * LI; i += 256) {
        const int to = i >> 7, ti = i & 127;
        al[to][ti] = at[(to * NB + b) * LI + ti];
    }
    __syncthreads();
    const int hc = h0 + (threadIdx.x & 127);
    const int rh = threadIdx.x >> 7;
    float acc[32];
    #pragma unroll
    for (int i = 0; i < 32; i++) acc[i] = 0.f;
    for (int t = 0; t < LI; t++) {
        const int64_t eo = ((int64_t)t * NB + b) * HD + hc;
        const float ev = b2f(eHi[eo]) + b2f(eLo[eo]);
        #pragma unroll
        for (int i = 0; i < 32; i++) acc[i] += ev * al[rh * 32 + i][t];
    }
    #pragma unroll
    for (int i = 0; i < 32; i++) {
        const int64_t jo = ((int64_t)(rh * 32 + i) * NB + b) * (2 * HD) + hc;
        bf16 hh = f2b(acc[i]);
        jHi[jo] = hh;
        jLo[jo] = f2b(acc[i] - b2f(hh));
    }
}

// copy RNN hi/lo into JIN[:, HD:2HD]
__global__ void rnncopy2_k(const bf16* __restrict__ rHi, const bf16* __restrict__ rLo,
                           bf16* __restrict__ jHi, bf16* __restrict__ jLo)
{
    const int idx = blockIdx.x * 256 + threadIdx.x;
    const int row = idx >> 8;
    const int c = idx & 255;
    ((uint2*)jHi)[(int64_t)row * 512 + 256 + c] = ((const uint2*)rHi)[idx];
    ((uint2*)jLo)[(int64_t)row * 512 + 256 + c] = ((const uint2*)rLo)[idx];
}

// =====================================================================
extern "C" void kernel_launch(void* const* d_in, const int* in_sizes, int n_in,
                              void* d_out, int out_size, void* d_ws, size_t ws_size,
                              hipStream_t stream)
{
    (void)in_sizes; (void)n_in; (void)out_size;
    const int*   in_tok   = (const int*)d_in[0];
    const int*   out_tok  = (const int*)d_in[2];
    const float* enc_emb  = (const float*)d_in[4];
    const float* enc_wih  = (const float*)d_in[5];
    const float* enc_whh  = (const float*)d_in[6];
    const float* enc_bih  = (const float*)d_in[7];
    const float* enc_bhh  = (const float*)d_in[8];
    const float* dec_emb  = (const float*)d_in[9];
    const float* dec_wih  = (const float*)d_in[10];
    const float* dec_whh  = (const float*)d_in[11];
    const float* dec_bih  = (const float*)d_in[12];
    const float* dec_bhh  = (const float*)d_in[13];
    const float* attn_W   = (const float*)d_in[14];
    const float* joiner_W = (const float*)d_in[15];
    const float* joiner_b = (const float*)d_in[16];
    const float* proj_W   = (const float*)d_in[17];
    const float* proj_b   = (const float*)d_in[18];
    float* logits   = (float*)d_out;
    float* attn_out = logits + (size_t)LO * NB * NV;

    const size_t MB = 1ull << 20;
    char* o = (char*)d_out;   // logits region = 250 MiB fp32
    bf16* XB0HI  = (bf16*)(o);               // 8 MiB (dead after L0 gi)
    bf16* XB0LO  = (bf16*)(o + 8 * MB);      // 8 MiB
    bf16* XB1HI  = (bf16*)(o + 16 * MB);     // 8 MiB
    bf16* XB1LO  = (bf16*)(o + 24 * MB);     // 8 MiB
    bf16* EOUTHI = (bf16*)(o + 32 * MB);     // 8 MiB (alive until ctx)
    bf16* EOUTLO = (bf16*)(o + 40 * MB);     // 8 MiB
    float* PENC  = (float*)(o + 48 * MB);    // 16 MiB fp32
    float* GI    = (float*)(o + 64 * MB);    // 48 MiB fp32
    float* DGI0  = (float*)(o + 112 * MB);   // 24 MiB fp32
    bf16* ENCH_HI = (bf16*)(o + 136 * MB);   // 8 MiB per-step slots
    bf16* ENCH_LO = (bf16*)(o + 144 * MB);   // 8 MiB
    bf16* JINHI  = (bf16*)(o + 152 * MB);    // 8 MiB (written post-dec)
    bf16* JINLO  = (bf16*)(o + 160 * MB);    // 8 MiB
    bf16* RNNHI  = (bf16*)(o + 168 * MB);    // 4 MiB
    bf16* RNNLO  = (bf16*)(o + 172 * MB);    // 4 MiB
    float* SC    = (float*)(o + 176 * MB);   // 1 MiB
    bf16* WencHi = (bf16*)(o + 177 * MB);    // 6 MiB
    bf16* WencLo = (bf16*)(o + 183 * MB);    // 6 MiB
    bf16* WdhHi  = (bf16*)(o + 189 * MB);    // 12 MiB
    bf16* WdhLo  = (bf16*)(o + 201 * MB);    // 12 MiB
    bf16* Wih1Hi = (bf16*)(o + 213 * MB);    // 6 MiB
    bf16* Wih1Lo = (bf16*)(o + 219 * MB);    // 6 MiB
    char* ba     = o + 225 * MB;             // 1 MiB: FL_E + FLAGD
    f32x4* PART  = (f32x4*)(o + 228 * MB);   // 0.5 MiB
    bf16* DEMBHI = (bf16*)(o + 229 * MB);    // 4 MiB
    bf16* DEMBLO = (bf16*)(o + 233 * MB);    // 4 MiB
    bf16* WATTB  = (bf16*)(o + 237 * MB);    // 2 MiB attn_W bf16
    bf16* WJOINB = (bf16*)(o + 239 * MB);    // 4 MiB joiner_W bf16
    bf16* WDIH0B = (bf16*)(o + 243 * MB);    // 6 MiB dec_wih[0] bf16 -> 249
    bf16* DECH_HI = XB0HI;                   // dec per-step slots (XB0 dead)
    bf16* DECH_LO = JINHI;                   // (JIN written post-dec)

    char* w = (char*)d_ws;
    bf16* VECSHI = (bf16*)(w);                        // 4 MiB
    bf16* VECSLO = (bf16*)(w + 4 * MB);               // 4 MiB
    float* EH32  = (float*)(w + 8 * MB);              // 512 KiB
    float* DH32  = (float*)(w + 8 * MB + 524288);     // 512 KiB
    const bool bigws = (ws_size >= (size_t)80 * MB);
    bf16* PROJW = (bf16*)(w + 12 * MB);               // 62.5 MiB if bigws

    int* FL_E  = (int*)(ba);                 // 64 x 8KB = 512 KiB
    int* FLAGD = (int*)(ba + 512 * 1024);    // 64 x 8KB = 512 KiB

    hipMemsetAsync(ba, 0, 1 * MB, stream);
    hipMemsetAsync(ENCH_HI, 0, (size_t)ESLOT * 2, stream);   // enc slot 0 = zeros
    hipMemsetAsync(ENCH_LO, 0, (size_t)ESLOT * 2, stream);

    // ---- pre-split recurrent weights (hi/lo) + GEMM weights (bf16) ----
    const int nEnc = NLAY * 2 * 3 * HHD * HHD;
    const int nDhh = NLAY * 3 * HD * HD;
    const int nIh1 = 3 * HD * HD;
    presplit_k<<<dim3((nEnc + 255) / 256), dim3(256), 0, stream>>>(enc_whh, WencHi, WencLo, nEnc);
    presplit_k<<<dim3((nDhh + 255) / 256), dim3(256), 0, stream>>>(dec_whh, WdhHi, WdhLo, nDhh);
    presplit_k<<<dim3((nIh1 + 255) / 256), dim3(256), 0, stream>>>(dec_wih + (size_t)3 * HD * HD, Wih1Hi, Wih1Lo, nIh1);
    presplitH_k<<<dim3((HD * HD + 255) / 256), dim3(256), 0, stream>>>(attn_W, WATTB, HD * HD);
    presplitH_k<<<dim3((HD * 2 * HD + 255) / 256), dim3(256), 0, stream>>>(joiner_W, WJOINB, HD * 2 * HD);
    presplitH_k<<<dim3((3 * HD * HD + 255) / 256), dim3(256), 0, stream>>>(dec_wih, WDIH0B, 3 * HD * HD);
    if (bigws)
        presplitH_k<<<dim3((NV * HD + 255) / 256), dim3(256), 0, stream>>>(proj_W, PROJW, NV * HD);

    // ---- decoder prep (bf16-W GEMM, m-major) ----
    embed2_k<<<dim3(LO * NB), dim3(256), 0, stream>>>(out_tok, dec_emb, DEMBHI, DEMBLO, 1);
    gemmBW_k<128, true, false, 0, 1><<<dim3(LO * NB / 128, 3 * HD / 128, 1), 256, 0, stream>>>(
        DEMBHI, DEMBLO, HD, 0, WDIH0B, HD, 0,
        DGI0, nullptr, nullptr, 3 * HD, 0, dec_bih, 0, HD);

    // ---- encoder (persistent, all-to-all hot-spin barrier) ----
    embed2_k<<<dim3(LI * NB), dim3(256), 0, stream>>>(in_tok, enc_emb, XB0HI, XB0LO, 0);
    for (int l = 0; l < NLAY; l++) {
        const bf16* XinH = l ? XB1HI : XB0HI;
        const bf16* XinL = l ? XB1LO : XB0LO;
        bf16* YoH = l ? EOUTHI : XB1HI;
        bf16* YoL = l ? EOUTLO : XB1LO;
        hipMemsetAsync(EH32, 0, (size_t)2 * 2 * NB * HHD * 4, stream);
        gemmWf_k<128, true, false, 0, 1><<<dim3(LI * NB / 128, 3 * HHD / 128, 2), 256, 0, stream>>>(
            XinH, XinL, HD, 0,
            enc_wih + (size_t)l * 2 * 3 * HHD * HD, HD, (int64_t)3 * HHD * HD,
            GI, nullptr, nullptr, 3 * HHD, (int64_t)LI * NB * 3 * HHD,
            enc_bih + l * 2 * 3 * HHD, 3 * HHD, HD);
        enc_persist_k<<<dim3(HHD / 16, 2), dim3(256), 0, stream>>>(
            GI,
            WencHi + (size_t)l * 2 * 3 * HHD * HHD,
            WencLo + (size_t)l * 2 * 3 * HHD * HHD,
            enc_bhh + l * 2 * 3 * HHD,
            EH32, ENCH_HI, ENCH_LO, YoH, YoL,
            DH32 + (size_t)l * NB * HD,
            DECH_HI + (size_t)l * NB * HD,
            DECH_LO + (size_t)l * NB * HD,
            FL_E);
        if (l == 0) hipMemsetAsync(FL_E, 0, 512 * 1024, stream);
    }

    // proj_enc = enc_outputs @ attn_W^T (bf16 W, m-major)
    gemmBW_k<128, false, false, 0, 1><<<dim3(LI * NB / 128, HD / 128, 1), 256, 0, stream>>>(
        EOUTHI, EOUTLO, HD, 0, WATTB, HD, 0,
        PENC, nullptr, nullptr, HD, 0, nullptr, 0, HD);

    // ---- decoder recurrence: 65 per-step launches ----
    for (int s = 0; s <= LO; s++)
        dec_step_k<<<dim3(HD / 16, 3), dim3(512), 0, stream>>>(
            DGI0,
            Wih1Hi, Wih1Lo,
            WdhHi, WdhLo,
            WdhHi + (size_t)3 * HD * HD, WdhLo + (size_t)3 * HD * HD,
            dec_bih + 3 * HD, dec_bhh, dec_bhh + 3 * HD,
            DH32, DECH_HI, DECH_LO, RNNHI, RNNLO, PART, FLAGD, s);

    // ---- batched epilogue ----
    gemmWf_k<64, false, false, 0, 0><<<dim3(1, 1, NB), 256, 0, stream>>>(
        RNNHI, RNNLO, (int64_t)NB * HD, HD, PENC, (int64_t)NB * HD, HD,
        SC, nullptr, nullptr, (int64_t)NB * LI, LI, nullptr, 0, HD);
    softmax_k<<<dim3(LO * NB), dim3(64), 0, stream>>>(SC, attn_out);
    ctx2_k<<<dim3(HD / 128, NB), dim3(256), 0, stream>>>(attn_out, EOUTHI, EOUTLO, JINHI, JINLO);
    rnncopy2_k<<<dim3(LO * NB * HD / 4 / 256), dim3(256), 0, stream>>>(RNNHI, RNNLO, JINHI, JINLO);
    gemmBW_k<128, true, true, 1, 1><<<dim3(LO * NB / 128, HD / 128, 1), 256, 0, stream>>>(
        JINHI, JINLO, 2 * HD, 0, WJOINB, 2 * HD, 0,
        nullptr, VECSHI, VECSLO, HD, 0, joiner_b, 0, 2 * HD);
    // logits GEMM (m-major, NOLO: A-hi only): bf16 W if it fits, else fp32.
    if (bigws) {
        gemmBW_k<128, true, false, 0, 1, true><<<dim3(LO * NB / 128, NV / 128, 1), 256, 0, stream>>>(
            VECSHI, VECSLO, HD, 0, PROJW, HD, 0,
            logits, nullptr, nullptr, NV, 0, proj_b, 0, HD);
    } else {
        gemmWf_k<128, true, false, 0, 1, true><<<dim3(LO * NB / 128, NV / 128, 1), 256, 0, stream>>>(
            VECSHI, VECSLO, HD, 0, proj_W, HD, 0,
            logits, nullptr, nullptr, NV, 0, proj_b, 0, HD);
    }
}